// Round 4
// baseline (420.680 us; speedup 1.0000x reference)
//
#include <hip/hip_runtime.h>
#include <hip/hip_bf16.h>

#define D_MODELC 1024
#define D_FFC    4096
#define N_HEADSC 16
#define BATCHC   2
#define SEQC     2048
#define M_TOK    (BATCHC*SEQC)   // 4096

typedef __attribute__((ext_vector_type(4))) float f32x4;
typedef __attribute__((ext_vector_type(8))) short s16x8;
using bf16_t = __hip_bfloat16;

static __device__ __forceinline__ unsigned short f2bf_u16(float f) {
  bf16_t h = __float2bfloat16(f);
  return __builtin_bit_cast(unsigned short, h);
}

#define ASYNC_COPY16(dst_lds, src_g) \
  __builtin_amdgcn_global_load_lds((const __attribute__((address_space(1))) void*)(src_g), \
                                   (__attribute__((address_space(3))) void*)(dst_lds), 16, 0, 0)

// ---------------- transpose + convert: in f32 [R][C] -> out bf16 [C][R] ----------------
__global__ __launch_bounds__(256) void k_transpose_f32_bf16(
    const float* __restrict__ in, bf16_t* __restrict__ out, int R, int C) {
  __shared__ float tile[32][33];
  int tx = threadIdx.x & 31, ty = threadIdx.x >> 5;  // 32 x 8
  int c0 = blockIdx.x * 32, r0 = blockIdx.y * 32;
#pragma unroll
  for (int i = 0; i < 4; ++i)
    tile[ty + i * 8][tx] = in[(size_t)(r0 + ty + i * 8) * C + c0 + tx];
  __syncthreads();
#pragma unroll
  for (int i = 0; i < 4; ++i)
    out[(size_t)(c0 + ty + i * 8) * R + r0 + tx] = __float2bfloat16(tile[tx][ty + i * 8]);
}

// ---------------- elementwise f32 -> bf16 (x4 vectorized) ----------------
__global__ __launch_bounds__(256) void k_f32_to_bf16(
    const float* __restrict__ in, bf16_t* __restrict__ out, int n4) {
  int i = blockIdx.x * 256 + threadIdx.x;
  if (i < n4) {
    float4 v = ((const float4*)in)[i];
    short4 o;
    o.x = (short)f2bf_u16(v.x);
    o.y = (short)f2bf_u16(v.y);
    o.z = (short)f2bf_u16(v.z);
    o.w = (short)f2bf_u16(v.w);
    ((short4*)out)[i] = o;
  }
}

// ---------------- pack qkv bias ----------------
__global__ __launch_bounds__(256) void k_pack_bias(
    const float* __restrict__ bq, const float* __restrict__ bk,
    const float* __restrict__ bv, float* __restrict__ out) {
  int i = blockIdx.x * 256 + threadIdx.x;  // 12 blocks * 256 = 3072
  float v = (i < 1024) ? bq[i] : (i < 2048) ? bk[i - 1024] : bv[i - 2048];
  out[i] = v;
}

// ---------------- GEMM: C[M][ldc] = epilogue(A[M][K] @ BT[N][K]^T + bias) ----------------
// mode 0: out bf16 = acc + bias
// mode 1: out bf16 = relu(acc + bias)
// mode 2: out f32  = acc + bias + res
// mode 3: out bf16 = (acc + bias) * (gcol < 1024 ? 0.125*log2e : 1)
#define GBM 128
#define GBN 128
#define GBK 32

__global__ __launch_bounds__(256, 2) void k_gemm(
    const bf16_t* __restrict__ A, const bf16_t* __restrict__ BT,
    const float* __restrict__ bias, const float* __restrict__ res,
    void* __restrict__ Cout, int M, int N, int K, int ldc, int mode) {
  __shared__ __align__(16) bf16_t Asm[GBM * GBK];
  __shared__ __align__(16) bf16_t Bsm[GBN * GBK];

  const int nbn = N / GBN;
  // T1: XCD-aware block swizzle (all grids are multiples of 8)
  const int nwg = gridDim.x;
  const int cpx = nwg >> 3;
  const int wg = (blockIdx.x & 7) * cpx + (blockIdx.x >> 3);
  const int mb = wg / nbn;
  const int nb = wg % nbn;
  const int row0 = mb * GBM, col0 = nb * GBN;

  const int tid = threadIdx.x;
  const int w = tid >> 6, lane = tid & 63;
  const int lr = lane & 15, lg = lane >> 4;
  const int wr = w >> 1, wc = w & 1;

  f32x4 acc[4][4];
#pragma unroll
  for (int m = 0; m < 4; ++m)
#pragma unroll
    for (int n = 0; n < 4; ++n) acc[m][n] = (f32x4){0.f, 0.f, 0.f, 0.f};

  for (int k0 = 0; k0 < K; k0 += GBK) {
    __syncthreads();
#pragma unroll
    for (int i = 0; i < 2; ++i) {
      int c = (i * 4 + w) * 64 + lane;      // chunk id, 16B each
      int rr = c >> 2, cg = (c & 3) * 8;    // row in tile, col group (8 bf16)
      ASYNC_COPY16(Asm + (size_t)(i * 4 + w) * 512,
                   A + (size_t)(row0 + rr) * K + k0 + cg);
      ASYNC_COPY16(Bsm + (size_t)(i * 4 + w) * 512,
                   BT + (size_t)(col0 + rr) * K + k0 + cg);
    }
    __syncthreads();
    s16x8 af[4], bfr[4];
#pragma unroll
    for (int m = 0; m < 4; ++m)
      af[m] = *(const s16x8*)(Asm + (size_t)(wr * 64 + m * 16 + lr) * GBK + lg * 8);
#pragma unroll
    for (int n = 0; n < 4; ++n)
      bfr[n] = *(const s16x8*)(Bsm + (size_t)(wc * 64 + n * 16 + lr) * GBK + lg * 8);
#pragma unroll
    for (int m = 0; m < 4; ++m)
#pragma unroll
      for (int n = 0; n < 4; ++n)
        acc[m][n] = __builtin_amdgcn_mfma_f32_16x16x32_bf16(af[m], bfr[n], acc[m][n], 0, 0, 0);
  }

  float* outf = (float*)Cout;
  bf16_t* outh = (bf16_t*)Cout;
#pragma unroll
  for (int m = 0; m < 4; ++m) {
    int grow = row0 + wr * 64 + m * 16 + lg * 4;
#pragma unroll
    for (int n = 0; n < 4; ++n) {
      int gcol = col0 + wc * 64 + n * 16 + lr;
      float bv = bias[gcol];
      float cs = (mode == 3 && gcol < 1024) ? 0.18033688f : 1.f;  // 0.125*log2(e)
#pragma unroll
      for (int r = 0; r < 4; ++r) {
        float v = (acc[m][n][r] + bv) * cs;
        size_t idx = (size_t)(grow + r) * ldc + gcol;
        if (mode == 2) {
          outf[idx] = v + res[idx];
        } else {
          if (mode == 1) v = fmaxf(v, 0.f);
          outh[idx] = __float2bfloat16(v);
        }
      }
    }
  }
}

// ---------------- flash attention (swapped-QK: P^T lane-local, deferred normalization) ----
// qkv: [4096][3072] bf16 (cols 0:1024 Q pre-scaled by 0.125*log2e, 1024:2048 K, 2048:3072 V)
// ctx: [4096][1024] bf16
// S^T = mfma(K_frag, Q_frag): lane (lr,lg) holds P^T[key=n*16+lg*4+r][q=lr].
// Pairs of consecutive keys pack to u32 -> 8 ds_write_b32 into per-wave PT[q][key]
// (160B row stride: conflict-free b128 reads). No per-tile reduction; row sums are a
// single lane-local scalar (q=lr), reduced once at the end.
__global__ __launch_bounds__(256, 3) void k_attn(
    const bf16_t* __restrict__ qkv, const int* __restrict__ mask,
    bf16_t* __restrict__ ctx) {
  const int bid = blockIdx.x;
  const int qt = bid & 31;
  const int h = (bid >> 5) & 15;
  const int b = bid >> 9;
  const int tid = threadIdx.x;
  const int w = tid >> 6, lane = tid & 63;
  const int lr = lane & 15, lg = lane >> 4;

  __shared__ __align__(16) unsigned int PT[4][16][40];  // per-wave P^T: [q][key-pair dw], stride 160B
  __shared__ __align__(16) bf16_t VT[2][64][80];        // V^T double buffer, stride 160B

  const int tokb = b * SEQC;
  const size_t tokq = (size_t)(tokb + qt * 64 + w * 16 + lr);
  const bf16_t* qp = qkv + tokq * 3072 + h * 64;
  s16x8 aq[2];
  aq[0] = *(const s16x8*)(qp + lg * 8);        // B-frag of Q: Q[q=lr][d=kst*32+lg*8..]
  aq[1] = *(const s16x8*)(qp + 32 + lg * 8);

  const int vkey = lane;
  const size_t vrow = (size_t)(tokb + vkey) * 3072 + 2048 + (size_t)h * 64;

  s16x8 vreg[2];
  s16x8 kreg[4][2];
  int4 mcur[4];

  // ---- prologue: stage tile 0 ----
  vreg[0] = *(const s16x8*)(qkv + vrow + w * 8);
  vreg[1] = *(const s16x8*)(qkv + vrow + (w + 4) * 8);
  {
    const bf16_t* e0 = (const bf16_t*)&vreg[0];
    const bf16_t* e1 = (const bf16_t*)&vreg[1];
#pragma unroll
    for (int j = 0; j < 8; ++j) VT[0][w * 8 + j][vkey] = e0[j];
#pragma unroll
    for (int j = 0; j < 8; ++j) VT[0][(w + 4) * 8 + j][vkey] = e1[j];
  }
#pragma unroll
  for (int n = 0; n < 4; ++n) {
#pragma unroll
    for (int kst = 0; kst < 2; ++kst)
      kreg[n][kst] = *(const s16x8*)(qkv + (size_t)(tokb + n * 16 + lr) * 3072 + 1024 + h * 64 + kst * 32 + lg * 8);
    mcur[n] = *(const int4*)&mask[tokb + n * 16 + lg * 4];
  }

  f32x4 o[4];
#pragma unroll
  for (int dn = 0; dn < 4; ++dn) o[dn] = (f32x4){0.f, 0.f, 0.f, 0.f};
  float lrow = 0.f;  // partial row sum for q = lr (this lane's keys only)

  __syncthreads();

  for (int kt = 0; kt < SEQC / 64; ++kt) {
    const int kb = kt * 64;
    const int cur = kt & 1, nxt = cur ^ 1;
    const bool more = (kt < SEQC / 64 - 1);

    // 1. issue V loads for tile kt+1 (consumed at step 7)
    if (more) {
      const size_t vr2 = vrow + (size_t)(kb + 64) * 3072;
      vreg[0] = *(const s16x8*)(qkv + vr2 + w * 8);
      vreg[1] = *(const s16x8*)(qkv + vr2 + (w + 4) * 8);
    }

    // 2. swapped QK^T: sf[n] = K_frag(n) x Q -> P^T[key=n*16+lg*4+r][q=lr]
    f32x4 sf[4];
#pragma unroll
    for (int n = 0; n < 4; ++n) sf[n] = (f32x4){0.f, 0.f, 0.f, 0.f};
#pragma unroll
    for (int kst = 0; kst < 2; ++kst)
#pragma unroll
      for (int n = 0; n < 4; ++n)
        sf[n] = __builtin_amdgcn_mfma_f32_16x16x32_bf16(kreg[n][kst], aq[kst], sf[n], 0, 0, 0);

    // 3. prefetch K frags + mask for tile kt+1
    int4 mnxt[4];
    if (more) {
#pragma unroll
      for (int n = 0; n < 4; ++n) {
#pragma unroll
        for (int kst = 0; kst < 2; ++kst)
          kreg[n][kst] = *(const s16x8*)(qkv + (size_t)(tokb + kb + 64 + n * 16 + lr) * 3072 + 1024 + h * 64 + kst * 32 + lg * 8);
        mnxt[n] = *(const int4*)&mask[tokb + kb + 64 + n * 16 + lg * 4];
      }
    }

    // 4. p = 2^s; masked -> 0; accumulate lane-local row sum; pack pairs; write PT
#pragma unroll
    for (int n = 0; n < 4; ++n) {
      const int* mc = (const int*)&mcur[n];
      float p0 = (mc[0] != 0) ? __builtin_exp2f(sf[n][0]) : 0.f;
      float p1 = (mc[1] != 0) ? __builtin_exp2f(sf[n][1]) : 0.f;
      float p2 = (mc[2] != 0) ? __builtin_exp2f(sf[n][2]) : 0.f;
      float p3 = (mc[3] != 0) ? __builtin_exp2f(sf[n][3]) : 0.f;
      lrow += (p0 + p1) + (p2 + p3);
      unsigned int w0 = (unsigned int)f2bf_u16(p0) | ((unsigned int)f2bf_u16(p1) << 16);
      unsigned int w1 = (unsigned int)f2bf_u16(p2) | ((unsigned int)f2bf_u16(p3) << 16);
      PT[w][lr][n * 8 + lg * 2 + 0] = w0;
      PT[w][lr][n * 8 + lg * 2 + 1] = w1;
    }

    // 5. PV: A-frag = PT[q=lr][k=ks*32+lg*8..], B-frag = VT rows (wave-private PT,
    //    compiler inserts the lgkmcnt for the same-wave read-after-write)
#pragma unroll
    for (int ks = 0; ks < 2; ++ks) {
      s16x8 ap = *(const s16x8*)&PT[w][lr][ks * 16 + lg * 4];
#pragma unroll
      for (int dn = 0; dn < 4; ++dn) {
        s16x8 bv8 = *(const s16x8*)&VT[cur][dn * 16 + lr][ks * 32 + lg * 8];
        o[dn] = __builtin_amdgcn_mfma_f32_16x16x32_bf16(ap, bv8, o[dn], 0, 0, 0);
      }
    }

    // 6. write-late: V tile kt+1 into VT[nxt]
    if (more) {
      const bf16_t* e0 = (const bf16_t*)&vreg[0];
      const bf16_t* e1 = (const bf16_t*)&vreg[1];
#pragma unroll
      for (int j = 0; j < 8; ++j) VT[nxt][w * 8 + j][vkey] = e0[j];
#pragma unroll
      for (int j = 0; j < 8; ++j) VT[nxt][(w + 4) * 8 + j][vkey] = e1[j];
#pragma unroll
      for (int n = 0; n < 4; ++n) mcur[n] = mnxt[n];
    }

    // 7. single barrier per iteration (VT buffer parity)
    __syncthreads();
  }

  // final: total row sum for q=lr = reduce over the 4 lg-groups
  lrow += __shfl_xor(lrow, 16);
  lrow += __shfl_xor(lrow, 32);
  // redistribute: output rows are q' = lg*4+r; totals live (uniform in lg) at lane q'
  float rs[4];
#pragma unroll
  for (int r = 0; r < 4; ++r) rs[r] = __shfl(lrow, lg * 4 + r);

  // write ctx (normalize here); o rows q = lg*4+r, col d = dn*16+lr
#pragma unroll
  for (int dn = 0; dn < 4; ++dn)
#pragma unroll
    for (int r = 0; r < 4; ++r) {
      int tok = tokb + qt * 64 + w * 16 + lg * 4 + r;
      float v = o[dn][r] / rs[r];
      ctx[(size_t)tok * 1024 + h * 64 + dn * 16 + lr] = __float2bfloat16(v);
    }
}

// ---------------- layernorm over rows of 1024 ----------------
__global__ __launch_bounds__(256) void k_ln(
    const float* __restrict__ in, const float* __restrict__ g, const float* __restrict__ be,
    float* __restrict__ outf, bf16_t* __restrict__ outh) {
  const int row = blockIdx.x, tid = threadIdx.x;
  const float4 v = ((const float4*)(in + (size_t)row * D_MODELC))[tid];
  float s1 = v.x + v.y + v.z + v.w;
  float s2 = v.x * v.x + v.y * v.y + v.z * v.z + v.w * v.w;
#pragma unroll
  for (int mm = 1; mm < 64; mm <<= 1) {
    s1 += __shfl_xor(s1, mm);
    s2 += __shfl_xor(s2, mm);
  }
  __shared__ float sa[4], sb[4];
  const int wv = tid >> 6;
  if ((tid & 63) == 0) { sa[wv] = s1; sb[wv] = s2; }
  __syncthreads();
  s1 = sa[0] + sa[1] + sa[2] + sa[3];
  s2 = sb[0] + sb[1] + sb[2] + sb[3];
  const float mu = s1 * (1.f / D_MODELC);
  const float var = s2 * (1.f / D_MODELC) - mu * mu;
  const float rs = rsqrtf(var + 1e-5f);
  const float4 gg = ((const float4*)g)[tid];
  const float4 bb = ((const float4*)be)[tid];
  float4 oo;
  oo.x = (v.x - mu) * rs * gg.x + bb.x;
  oo.y = (v.y - mu) * rs * gg.y + bb.y;
  oo.z = (v.z - mu) * rs * gg.z + bb.z;
  oo.w = (v.w - mu) * rs * gg.w + bb.w;
  ((float4*)(outf + (size_t)row * D_MODELC))[tid] = oo;
  if (outh) {
    short4 ob;
    ob.x = (short)f2bf_u16(oo.x);
    ob.y = (short)f2bf_u16(oo.y);
    ob.z = (short)f2bf_u16(oo.z);
    ob.w = (short)f2bf_u16(oo.w);
    ((short4*)(outh + (size_t)row * D_MODELC))[tid] = ob;
  }
}

extern "C" void kernel_launch(void* const* d_in, const int* in_sizes, int n_in,
                              void* d_out, int out_size, void* d_ws, size_t ws_size,
                              hipStream_t stream) {
  (void)in_sizes; (void)n_in; (void)out_size; (void)ws_size;
  const float* x   = (const float*)d_in[0];
  const int* mask  = (const int*)d_in[1];
  const float* Wq  = (const float*)d_in[2];
  const float* bq  = (const float*)d_in[3];
  const float* Wk  = (const float*)d_in[4];
  const float* bk  = (const float*)d_in[5];
  const float* Wv  = (const float*)d_in[6];
  const float* bv  = (const float*)d_in[7];
  const float* Wo  = (const float*)d_in[8];
  const float* bo  = (const float*)d_in[9];
  const float* W1  = (const float*)d_in[10];
  const float* b1  = (const float*)d_in[11];
  const float* W2  = (const float*)d_in[12];
  const float* b2  = (const float*)d_in[13];
  const float* g1  = (const float*)d_in[14];
  const float* be1 = (const float*)d_in[15];
  const float* g2  = (const float*)d_in[16];
  const float* be2 = (const float*)d_in[17];

  char* ws = (char*)d_ws;
  const size_t D = D_MODELC, F = D_FFC, M = M_TOK;
  const size_t SZ_X16  = M * D * 2;        // 8.4 MB
  const size_t SZ_QKV  = M * 3 * D * 2;    // 25.2 MB
  bf16_t* x16   = (bf16_t*)ws;
  bf16_t* ff1   = (bf16_t*)ws;             // aliases x16+qkv (both dead by FF1)
  bf16_t* qkvb  = (bf16_t*)(ws + SZ_X16);
  size_t off = SZ_X16 + SZ_QKV;
  bf16_t* ctx   = (bf16_t*)(ws + off); off += M * D * 2;
  bf16_t* wqkvT = (bf16_t*)(ws + off); off += 3 * D * D * 2;
  bf16_t* woT   = (bf16_t*)(ws + off); off += D * D * 2;
  bf16_t* w1T   = (bf16_t*)(ws + off); off += D * F * 2;
  bf16_t* w2T   = (bf16_t*)(ws + off); off += D * F * 2;
  float*  ln1in = (float*)(ws + off);  off += M * D * 4;
  float*  hbuf  = (float*)(ws + off);  off += M * D * 4;
  bf16_t* h16   = (bf16_t*)(ws + off); off += M * D * 2;
  float*  ln2in = (float*)(ws + off);  off += M * D * 4;
  float*  bqkv  = (float*)(ws + off);  off += 3 * D * 4;

  // --- weight prep ---
  k_transpose_f32_bf16<<<dim3(32, 32), 256, 0, stream>>>(Wq, wqkvT, 1024, 1024);
  k_transpose_f32_bf16<<<dim3(32, 32), 256, 0, stream>>>(Wk, wqkvT + 1024 * 1024, 1024, 1024);
  k_transpose_f32_bf16<<<dim3(32, 32), 256, 0, stream>>>(Wv, wqkvT + 2 * 1024 * 1024, 1024, 1024);
  k_transpose_f32_bf16<<<dim3(32, 32), 256, 0, stream>>>(Wo, woT, 1024, 1024);
  k_transpose_f32_bf16<<<dim3(128, 32), 256, 0, stream>>>(W1, w1T, 1024, 4096);
  k_transpose_f32_bf16<<<dim3(32, 128), 256, 0, stream>>>(W2, w2T, 4096, 1024);
  k_f32_to_bf16<<<4096, 256, 0, stream>>>(x, x16, (int)(M * D / 4));
  k_pack_bias<<<12, 256, 0, stream>>>(bq, bk, bv, bqkv);

  // --- QKV projection: [4096][3072], Q columns pre-scaled by 0.125*log2e ---
  k_gemm<<<(4096 / GBM) * (3072 / GBN), 256, 0, stream>>>(
      x16, wqkvT, bqkv, nullptr, qkvb, 4096, 3072, 1024, 3072, 3);

  // --- attention ---
  k_attn<<<BATCHC * N_HEADSC * (SEQC / 64), 256, 0, stream>>>(qkvb, mask, ctx);

  // --- output projection + residual -> ln1in ---
  k_gemm<<<(4096 / GBM) * (1024 / GBN), 256, 0, stream>>>(
      ctx, woT, bo, x, ln1in, 4096, 1024, 1024, 1024, 2);
  k_ln<<<4096, 256, 0, stream>>>(ln1in, g1, be1, hbuf, h16);

  // --- FFN ---
  k_gemm<<<(4096 / GBM) * (4096 / GBN), 256, 0, stream>>>(
      h16, w1T, b1, nullptr, ff1, 4096, 4096, 1024, 4096, 1);
  k_gemm<<<(4096 / GBM) * (1024 / GBN), 256, 0, stream>>>(
      ff1, w2T, b2, hbuf, ln2in, 4096, 1024, 4096, 1024, 2);
  k_ln<<<4096, 256, 0, stream>>>(ln2in, g2, be2, (float*)d_out, nullptr);
}

// Round 5
// 329.874 us; speedup vs baseline: 1.2753x; 1.2753x over previous
//
#include <hip/hip_runtime.h>
#include <hip/hip_bf16.h>

#define D_MODELC 1024
#define D_FFC    4096
#define N_HEADSC 16
#define BATCHC   2
#define SEQC     2048
#define M_TOK    (BATCHC*SEQC)   // 4096

typedef __attribute__((ext_vector_type(4)))  float f32x4;
typedef __attribute__((ext_vector_type(16))) float f32x16;
typedef __attribute__((ext_vector_type(8)))  short s16x8;
using bf16_t = __hip_bfloat16;

static __device__ __forceinline__ unsigned short f2bf_u16(float f) {
  bf16_t h = __float2bfloat16(f);
  return __builtin_bit_cast(unsigned short, h);
}

static __device__ __forceinline__ unsigned int cvt_pk_bf16(float lo, float hi2) {
  unsigned int r;
  asm("v_cvt_pk_bf16_f32 %0, %1, %2" : "=v"(r) : "v"(lo), "v"(hi2));
  return r;
}

#define ASYNC_COPY16(dst_lds, src_g) \
  __builtin_amdgcn_global_load_lds((const __attribute__((address_space(1))) void*)(src_g), \
                                   (__attribute__((address_space(3))) void*)(dst_lds), 16, 0, 0)

// ---------------- transpose + convert: in f32 [R][C] -> out bf16 [C][R] ----------------
__global__ __launch_bounds__(256) void k_transpose_f32_bf16(
    const float* __restrict__ in, bf16_t* __restrict__ out, int R, int C) {
  __shared__ float tile[32][33];
  int tx = threadIdx.x & 31, ty = threadIdx.x >> 5;  // 32 x 8
  int c0 = blockIdx.x * 32, r0 = blockIdx.y * 32;
#pragma unroll
  for (int i = 0; i < 4; ++i)
    tile[ty + i * 8][tx] = in[(size_t)(r0 + ty + i * 8) * C + c0 + tx];
  __syncthreads();
#pragma unroll
  for (int i = 0; i < 4; ++i)
    out[(size_t)(c0 + ty + i * 8) * R + r0 + tx] = __float2bfloat16(tile[tx][ty + i * 8]);
}

// ---------------- elementwise f32 -> bf16 (x4 vectorized) ----------------
__global__ __launch_bounds__(256) void k_f32_to_bf16(
    const float* __restrict__ in, bf16_t* __restrict__ out, int n4) {
  int i = blockIdx.x * 256 + threadIdx.x;
  if (i < n4) {
    float4 v = ((const float4*)in)[i];
    short4 o;
    o.x = (short)f2bf_u16(v.x);
    o.y = (short)f2bf_u16(v.y);
    o.z = (short)f2bf_u16(v.z);
    o.w = (short)f2bf_u16(v.w);
    ((short4*)out)[i] = o;
  }
}

// ---------------- pack qkv bias ----------------
__global__ __launch_bounds__(256) void k_pack_bias(
    const float* __restrict__ bq, const float* __restrict__ bk,
    const float* __restrict__ bv, float* __restrict__ out) {
  int i = blockIdx.x * 256 + threadIdx.x;  // 12 blocks * 256 = 3072
  float v = (i < 1024) ? bq[i] : (i < 2048) ? bk[i - 1024] : bv[i - 2048];
  out[i] = v;
}

// ---------------- GEMM: C[M][ldc] = epilogue(A[M][K] @ BT[N][K]^T + bias) ----------------
// mode 0: out bf16 = acc + bias
// mode 1: out bf16 = relu(acc + bias)
// mode 2: out f32  = acc + bias + res
// mode 3: out bf16 = (acc + bias) * (gcol < 1024 ? 0.125*log2e : 1)
#define GBM 128
#define GBN 128
#define GBK 32

__global__ __launch_bounds__(256, 2) void k_gemm(
    const bf16_t* __restrict__ A, const bf16_t* __restrict__ BT,
    const float* __restrict__ bias, const float* __restrict__ res,
    void* __restrict__ Cout, int M, int N, int K, int ldc, int mode) {
  __shared__ __align__(16) bf16_t Asm[GBM * GBK];
  __shared__ __align__(16) bf16_t Bsm[GBN * GBK];

  const int nbn = N / GBN;
  const int nwg = gridDim.x;
  const int cpx = nwg >> 3;
  const int wg = (blockIdx.x & 7) * cpx + (blockIdx.x >> 3);
  const int mb = wg / nbn;
  const int nb = wg % nbn;
  const int row0 = mb * GBM, col0 = nb * GBN;

  const int tid = threadIdx.x;
  const int w = tid >> 6, lane = tid & 63;
  const int lr = lane & 15, lg = lane >> 4;
  const int wr = w >> 1, wc = w & 1;

  f32x4 acc[4][4];
#pragma unroll
  for (int m = 0; m < 4; ++m)
#pragma unroll
    for (int n = 0; n < 4; ++n) acc[m][n] = (f32x4){0.f, 0.f, 0.f, 0.f};

  for (int k0 = 0; k0 < K; k0 += GBK) {
    __syncthreads();
#pragma unroll
    for (int i = 0; i < 2; ++i) {
      int c = (i * 4 + w) * 64 + lane;      // chunk id, 16B each
      int rr = c >> 2, cg = (c & 3) * 8;    // row in tile, col group (8 bf16)
      ASYNC_COPY16(Asm + (size_t)(i * 4 + w) * 512,
                   A + (size_t)(row0 + rr) * K + k0 + cg);
      ASYNC_COPY16(Bsm + (size_t)(i * 4 + w) * 512,
                   BT + (size_t)(col0 + rr) * K + k0 + cg);
    }
    __syncthreads();
    s16x8 af[4], bfr[4];
#pragma unroll
    for (int m = 0; m < 4; ++m)
      af[m] = *(const s16x8*)(Asm + (size_t)(wr * 64 + m * 16 + lr) * GBK + lg * 8);
#pragma unroll
    for (int n = 0; n < 4; ++n)
      bfr[n] = *(const s16x8*)(Bsm + (size_t)(wc * 64 + n * 16 + lr) * GBK + lg * 8);
#pragma unroll
    for (int m = 0; m < 4; ++m)
#pragma unroll
      for (int n = 0; n < 4; ++n)
        acc[m][n] = __builtin_amdgcn_mfma_f32_16x16x32_bf16(af[m], bfr[n], acc[m][n], 0, 0, 0);
  }

  float* outf = (float*)Cout;
  bf16_t* outh = (bf16_t*)Cout;
#pragma unroll
  for (int m = 0; m < 4; ++m) {
    int grow = row0 + wr * 64 + m * 16 + lg * 4;
#pragma unroll
    for (int n = 0; n < 4; ++n) {
      int gcol = col0 + wc * 64 + n * 16 + lr;
      float bv = bias[gcol];
      float cs = (mode == 3 && gcol < 1024) ? 0.18033688f : 1.f;  // 0.125*log2(e)
#pragma unroll
      for (int r = 0; r < 4; ++r) {
        float v = (acc[m][n][r] + bv) * cs;
        size_t idx = (size_t)(grow + r) * ldc + gcol;
        if (mode == 2) {
          outf[idx] = v + res[idx];
        } else {
          if (mode == 1) v = fmaxf(v, 0.f);
          outh[idx] = __float2bfloat16(v);
        }
      }
    }
  }
}

// ---------------- flash attention: 32x32 MFMA, lane-local softmax ----------------
// qkv: [4096][3072] bf16 (Q pre-scaled by 0.125*log2e, K at +1024, V at +2048)
// Per block: 4 waves x 32 q-rows = 128 q. KVBLK = 64. Swapped QK^T (mfma(K,Q)) puts
// P^T[key][q=lane&31] lane-local: softmax = 32 exp2+mul+add per tile, no cross-lane.
// P repack for PV A-frag: 16 cvt_pk + 8 shfl_xor(32). K staged via global_load_lds with
// pre-swizzled source + XOR-swizzled ds_read_b128; V^T staged at stride 72.
// Rowsum deferred; single shuffle-reduce after the K-loop.
__global__ __launch_bounds__(256, 2) void k_attn(
    const bf16_t* __restrict__ qkv, const int* __restrict__ mask,
    bf16_t* __restrict__ ctx) {
  const int bid = blockIdx.x;
  const int qt = bid & 15;          // 16 q-tiles of 128
  const int h  = (bid >> 4) & 15;
  const int b  = bid >> 8;
  const int tid = threadIdx.x;
  const int w = tid >> 6, lane = tid & 63;
  const int l31 = lane & 31, hi = lane >> 5;

  __shared__ __align__(16) bf16_t Kl[2][64][64];   // XOR-swizzled (seg ^= row&7)
  __shared__ __align__(16) bf16_t VT[2][64][72];   // V^T, stride 144B
  __shared__ __align__(16) float  mskf[2][64];

  const int tokb = b * SEQC;
  const int q0 = qt * 128 + w * 32;

  // Q B-frags: qfrag[step] = Q[tokb+q0+l31][16*step + 8*hi .. +8]  (B: col=l31, k=8*hi+j)
  s16x8 qfrag[4];
  {
    const bf16_t* qp = qkv + (size_t)(tokb + q0 + l31) * 3072 + h * 64 + hi * 8;
#pragma unroll
    for (int s = 0; s < 4; ++s) qfrag[s] = *(const s16x8*)(qp + s * 16);
  }

  char* klc = (char*)&Kl[0][0][0];
  char* vtc = (char*)&VT[0][0][0];

  s16x8 vr[2];
  float mreg = 1.f;

  // ---- staging helpers (inline) ----
  // K tile -> LDS buf via global_load_lds; source seg pre-swizzled so LDS[row][seg]
  // holds K[row][seg ^ (row&7)]; read at (c ^ (row&7)) recovers K[row][c].
#define STAGE_K(buf, kb)                                                              \
  {                                                                                   \
    _Pragma("unroll")                                                                 \
    for (int ii = 0; ii < 2; ++ii) {                                                  \
      int chunk = w * 2 + ii;                                                         \
      int row = chunk * 8 + (lane >> 3);                                              \
      int seg = (lane & 7) ^ (row & 7);                                               \
      const bf16_t* src = qkv + (size_t)(tokb + (kb) + row) * 3072 + 1024 + h * 64 + seg * 8; \
      ASYNC_COPY16(&Kl[buf][chunk * 8][0], src);                                      \
    }                                                                                 \
  }

#define LOAD_V(kb)                                                                    \
  {                                                                                   \
    _Pragma("unroll")                                                                 \
    for (int i = 0; i < 2; ++i) {                                                     \
      int c = tid + i * 256;                                                          \
      int key = c & 63, d0 = (c >> 6) * 8;                                            \
      vr[i] = *(const s16x8*)(qkv + (size_t)(tokb + (kb) + key) * 3072 + 2048 + h * 64 + d0); \
    }                                                                                 \
  }

#define WRITE_V(buf)                                                                  \
  {                                                                                   \
    _Pragma("unroll")                                                                 \
    for (int i = 0; i < 2; ++i) {                                                     \
      int c = tid + i * 256;                                                          \
      int key = c & 63, d0 = (c >> 6) * 8;                                            \
      const bf16_t* e = (const bf16_t*)&vr[i];                                        \
      _Pragma("unroll")                                                               \
      for (int j = 0; j < 8; ++j) {                                                   \
        int d = d0 + j;                                                               \
        *(bf16_t*)(vtc + (buf) * 9216 + d * 144 + (key >> 3) * 16 + (key & 7) * 2) = e[j]; \
      }                                                                               \
    }                                                                                 \
  }

  // ---- prologue: stage tile 0 ----
  STAGE_K(0, 0)
  LOAD_V(0)
  if (tid < 64) mreg = mask[tokb + tid] ? 1.f : 0.f;
  WRITE_V(0)
  if (tid < 64) mskf[0][tid] = mreg;

  f32x16 o[2];
#pragma unroll
  for (int d = 0; d < 2; ++d)
#pragma unroll
    for (int i = 0; i < 16; ++i) o[d][i] = 0.f;
  float psum = 0.f;

  __syncthreads();

  for (int kt = 0; kt < SEQC / 64; ++kt) {
    const int kb = kt * 64;
    const int cur = kt & 1, nxt = cur ^ 1;
    const bool more = (kt < SEQC / 64 - 1);

    // 1. issue next-tile staging (K async->LDS[nxt], V->regs, mask->reg)
    if (more) {
      STAGE_K(nxt, kb + 64)
      LOAD_V(kb + 64)
      if (tid < 64) mreg = mask[tokb + kb + 64 + tid] ? 1.f : 0.f;
    }

    // 2. swapped QK^T: st[kb2] = K(rows kb2*32..+32) x Q^T -> S^T[key][q=l31]
    f32x16 st[2];
#pragma unroll
    for (int kk = 0; kk < 2; ++kk)
#pragma unroll
      for (int i = 0; i < 16; ++i) st[kk][i] = 0.f;
#pragma unroll
    for (int step = 0; step < 4; ++step) {
#pragma unroll
      for (int kb2 = 0; kb2 < 2; ++kb2) {
        int key = kb2 * 32 + l31;
        int seg = (2 * step + hi) ^ (lane & 7);
        s16x8 kf = *(const s16x8*)(klc + cur * 8192 + key * 128 + seg * 16);
        st[kb2] = __builtin_amdgcn_mfma_f32_32x32x16_bf16(kf, qfrag[step], st[kb2], 0, 0, 0);
      }
    }

    // 3+4. softmax (lane-local) + pack + partner exchange -> PV A-frags pf[4]
    // key offset of st[kb2] reg r: (r&3) + 8*(r>>2) + 4*hi  (+32*kb2)
    s16x8 pf[4];
#pragma unroll
    for (int kb2 = 0; kb2 < 2; ++kb2) {
      float pa[16];
#pragma unroll
      for (int g = 0; g < 4; ++g) {
        f32x4 mm = *(const f32x4*)((char*)&mskf[cur][0] + (kb2 * 128 + g * 32 + hi * 16));
#pragma unroll
        for (int rr = 0; rr < 4; ++rr) {
          float e = __builtin_exp2f(st[kb2][g * 4 + rr]) * mm[rr];
          pa[g * 4 + rr] = e;
          psum += e;
        }
      }
      // pack pairs: wv[u] covers key-pair pi = {2hi,2hi+1,4+2hi,5+2hi,8+2hi,9+2hi,12+2hi,13+2hi}[u]
      unsigned int wv[8];
#pragma unroll
      for (int u = 0; u < 8; ++u) wv[u] = cvt_pk_bf16(pa[2 * u], pa[2 * u + 1]);
      // exchange with partner lane (l^32, same q): each swap trades one word each way
      unsigned int x1 = hi ? wv[0] : wv[2]; x1 = (unsigned int)__shfl_xor((int)x1, 32);
      unsigned int x2 = hi ? wv[1] : wv[3]; x2 = (unsigned int)__shfl_xor((int)x2, 32);
      unsigned int x3 = hi ? wv[4] : wv[6]; x3 = (unsigned int)__shfl_xor((int)x3, 32);
      unsigned int x4 = hi ? wv[5] : wv[7]; x4 = (unsigned int)__shfl_xor((int)x4, 32);
      // assemble A-frag words (pi = 8*ks' + 4*hi + w')
      unsigned int f0[4], f1[4];
      f0[0] = hi ? x1 : wv[0];  f0[1] = hi ? x2 : wv[1];
      f0[2] = hi ? wv[2] : x1;  f0[3] = hi ? wv[3] : x2;
      f1[0] = hi ? x3 : wv[4];  f1[1] = hi ? x4 : wv[5];
      f1[2] = hi ? wv[6] : x3;  f1[3] = hi ? wv[7] : x4;
      pf[kb2 * 2 + 0] = __builtin_bit_cast(s16x8, *(ulong2*)f0);
      pf[kb2 * 2 + 1] = __builtin_bit_cast(s16x8, *(ulong2*)f1);
    }

    // 5. PV: o[dblk] += P(frag ks) x V^T rows; B-frag = VT[d=dblk*32+l31][16ks+8hi ..+8]
#pragma unroll
    for (int ks = 0; ks < 4; ++ks) {
#pragma unroll
      for (int dblk = 0; dblk < 2; ++dblk) {
        int d = dblk * 32 + l31;
        s16x8 vf = *(const s16x8*)(vtc + cur * 9216 + d * 144 + (2 * ks + hi) * 16);
        o[dblk] = __builtin_amdgcn_mfma_f32_32x32x16_bf16(pf[ks], vf, o[dblk], 0, 0, 0);
      }
    }

    // 6. write-late staging into nxt
    if (more) {
      WRITE_V(nxt)
      if (tid < 64) mskf[nxt][tid] = mreg;
    }

    // 7. single barrier (buffer parity)
    __syncthreads();
  }

  // ---- final: rowsum reduce + normalize + write ----
  psum += __shfl_xor(psum, 32);   // combine the two 32-key halves (same q = l31)
  float rs[16];
#pragma unroll
  for (int r = 0; r < 16; ++r) {
    int qq = (r & 3) + 8 * (r >> 2) + 4 * hi;  // o-row q' for acc reg r
    rs[r] = __shfl(psum, qq);                   // total for q' lives at lane q'
  }
#pragma unroll
  for (int dblk = 0; dblk < 2; ++dblk)
#pragma unroll
    for (int r = 0; r < 16; ++r) {
      int qq = (r & 3) + 8 * (r >> 2) + 4 * hi;
      int tok = tokb + q0 + qq;
      ctx[(size_t)tok * 1024 + h * 64 + dblk * 32 + l31] = __float2bfloat16(o[dblk][r] / rs[r]);
    }
#undef STAGE_K
#undef LOAD_V
#undef WRITE_V
}

// ---------------- layernorm over rows of 1024 ----------------
__global__ __launch_bounds__(256) void k_ln(
    const float* __restrict__ in, const float* __restrict__ g, const float* __restrict__ be,
    float* __restrict__ outf, bf16_t* __restrict__ outh) {
  const int row = blockIdx.x, tid = threadIdx.x;
  const float4 v = ((const float4*)(in + (size_t)row * D_MODELC))[tid];
  float s1 = v.x + v.y + v.z + v.w;
  float s2 = v.x * v.x + v.y * v.y + v.z * v.z + v.w * v.w;
#pragma unroll
  for (int mm = 1; mm < 64; mm <<= 1) {
    s1 += __shfl_xor(s1, mm);
    s2 += __shfl_xor(s2, mm);
  }
  __shared__ float sa[4], sb[4];
  const int wv = tid >> 6;
  if ((tid & 63) == 0) { sa[wv] = s1; sb[wv] = s2; }
  __syncthreads();
  s1 = sa[0] + sa[1] + sa[2] + sa[3];
  s2 = sb[0] + sb[1] + sb[2] + sb[3];
  const float mu = s1 * (1.f / D_MODELC);
  const float var = s2 * (1.f / D_MODELC) - mu * mu;
  const float rs = rsqrtf(var + 1e-5f);
  const float4 gg = ((const float4*)g)[tid];
  const float4 bb = ((const float4*)be)[tid];
  float4 oo;
  oo.x = (v.x - mu) * rs * gg.x + bb.x;
  oo.y = (v.y - mu) * rs * gg.y + bb.y;
  oo.z = (v.z - mu) * rs * gg.z + bb.z;
  oo.w = (v.w - mu) * rs * gg.w + bb.w;
  ((float4*)(outf + (size_t)row * D_MODELC))[tid] = oo;
  if (outh) {
    short4 ob;
    ob.x = (short)f2bf_u16(oo.x);
    ob.y = (short)f2bf_u16(oo.y);
    ob.z = (short)f2bf_u16(oo.z);
    ob.w = (short)f2bf_u16(oo.w);
    ((short4*)(outh + (size_t)row * D_MODELC))[tid] = ob;
  }
}

extern "C" void kernel_launch(void* const* d_in, const int* in_sizes, int n_in,
                              void* d_out, int out_size, void* d_ws, size_t ws_size,
                              hipStream_t stream) {
  (void)in_sizes; (void)n_in; (void)out_size; (void)ws_size;
  const float* x   = (const float*)d_in[0];
  const int* mask  = (const int*)d_in[1];
  const float* Wq  = (const float*)d_in[2];
  const float* bq  = (const float*)d_in[3];
  const float* Wk  = (const float*)d_in[4];
  const float* bk  = (const float*)d_in[5];
  const float* Wv  = (const float*)d_in[6];
  const float* bv  = (const float*)d_in[7];
  const float* Wo  = (const float*)d_in[8];
  const float* bo  = (const float*)d_in[9];
  const float* W1  = (const float*)d_in[10];
  const float* b1  = (const float*)d_in[11];
  const float* W2  = (const float*)d_in[12];
  const float* b2  = (const float*)d_in[13];
  const float* g1  = (const float*)d_in[14];
  const float* be1 = (const float*)d_in[15];
  const float* g2  = (const float*)d_in[16];
  const float* be2 = (const float*)d_in[17];

  char* ws = (char*)d_ws;
  const size_t D = D_MODELC, F = D_FFC, M = M_TOK;
  const size_t SZ_X16  = M * D * 2;        // 8.4 MB
  const size_t SZ_QKV  = M * 3 * D * 2;    // 25.2 MB
  bf16_t* x16   = (bf16_t*)ws;
  bf16_t* ff1   = (bf16_t*)ws;             // aliases x16+qkv (both dead by FF1)
  bf16_t* qkvb  = (bf16_t*)(ws + SZ_X16);
  size_t off = SZ_X16 + SZ_QKV;
  bf16_t* ctx   = (bf16_t*)(ws + off); off += M * D * 2;
  bf16_t* wqkvT = (bf16_t*)(ws + off); off += 3 * D * D * 2;
  bf16_t* woT   = (bf16_t*)(ws + off); off += D * D * 2;
  bf16_t* w1T   = (bf16_t*)(ws + off); off += D * F * 2;
  bf16_t* w2T   = (bf16_t*)(ws + off); off += D * F * 2;
  float*  ln1in = (float*)(ws + off);  off += M * D * 4;
  float*  hbuf  = (float*)(ws + off);  off += M * D * 4;
  bf16_t* h16   = (bf16_t*)(ws + off); off += M * D * 2;
  float*  ln2in = (float*)(ws + off);  off += M * D * 4;
  float*  bqkv  = (float*)(ws + off);  off += 3 * D * 4;

  // --- weight prep ---
  k_transpose_f32_bf16<<<dim3(32, 32), 256, 0, stream>>>(Wq, wqkvT, 1024, 1024);
  k_transpose_f32_bf16<<<dim3(32, 32), 256, 0, stream>>>(Wk, wqkvT + 1024 * 1024, 1024, 1024);
  k_transpose_f32_bf16<<<dim3(32, 32), 256, 0, stream>>>(Wv, wqkvT + 2 * 1024 * 1024, 1024, 1024);
  k_transpose_f32_bf16<<<dim3(32, 32), 256, 0, stream>>>(Wo, woT, 1024, 1024);
  k_transpose_f32_bf16<<<dim3(128, 32), 256, 0, stream>>>(W1, w1T, 1024, 4096);
  k_transpose_f32_bf16<<<dim3(32, 128), 256, 0, stream>>>(W2, w2T, 4096, 1024);
  k_f32_to_bf16<<<4096, 256, 0, stream>>>(x, x16, (int)(M * D / 4));
  k_pack_bias<<<12, 256, 0, stream>>>(bq, bk, bv, bqkv);

  // --- QKV projection: [4096][3072], Q columns pre-scaled by 0.125*log2e ---
  k_gemm<<<(4096 / GBM) * (3072 / GBN), 256, 0, stream>>>(
      x16, wqkvT, bqkv, nullptr, qkvb, 4096, 3072, 1024, 3072, 3);

  // --- attention: 512 blocks (2*16*16), 4 waves x 32 q-rows ---
  k_attn<<<BATCHC * N_HEADSC * (SEQC / 128), 256, 0, stream>>>(qkvb, mask, ctx);

  // --- output projection + residual -> ln1in ---
  k_gemm<<<(4096 / GBM) * (1024 / GBN), 256, 0, stream>>>(
      ctx, woT, bo, x, ln1in, 4096, 1024, 1024, 1024, 2);
  k_ln<<<4096, 256, 0, stream>>>(ln1in, g1, be1, hbuf, h16);

  // --- FFN ---
  k_gemm<<<(4096 / GBM) * (4096 / GBN), 256, 0, stream>>>(
      h16, w1T, b1, nullptr, ff1, 4096, 4096, 1024, 4096, 1);
  k_gemm<<<(4096 / GBM) * (1024 / GBN), 256, 0, stream>>>(
      ff1, w2T, b2, hbuf, ln2in, 4096, 1024, 4096, 1024, 2);
  k_ln<<<4096, 256, 0, stream>>>(ln2in, g2, be2, (float*)d_out, nullptr);
}

// Round 6
// 275.165 us; speedup vs baseline: 1.5288x; 1.1988x over previous
//
#include <hip/hip_runtime.h>
#include <hip/hip_bf16.h>

#define D_MODELC 1024
#define D_FFC    4096
#define N_HEADSC 16
#define BATCHC   2
#define SEQC     2048
#define M_TOK    (BATCHC*SEQC)   // 4096

typedef __attribute__((ext_vector_type(4)))  float f32x4;
typedef __attribute__((ext_vector_type(16))) float f32x16;
typedef __attribute__((ext_vector_type(8)))  short s16x8;
using bf16_t = __hip_bfloat16;

static __device__ __forceinline__ unsigned short f2bf_u16(float f) {
  bf16_t h = __float2bfloat16(f);
  return __builtin_bit_cast(unsigned short, h);
}

static __device__ __forceinline__ unsigned int cvt_pk_bf16(float lo, float hi2) {
  unsigned int r;
  asm("v_cvt_pk_bf16_f32 %0, %1, %2" : "=v"(r) : "v"(lo), "v"(hi2));
  return r;
}

#define ASYNC_COPY16(dst_lds, src_g) \
  __builtin_amdgcn_global_load_lds((const __attribute__((address_space(1))) void*)(src_g), \
                                   (__attribute__((address_space(3))) void*)(dst_lds), 16, 0, 0)

// ---------------- transpose + convert: in f32 [R][C] -> out bf16 [C][R] ----------------
__global__ __launch_bounds__(256) void k_transpose_f32_bf16(
    const float* __restrict__ in, bf16_t* __restrict__ out, int R, int C) {
  __shared__ float tile[32][33];
  int tx = threadIdx.x & 31, ty = threadIdx.x >> 5;  // 32 x 8
  int c0 = blockIdx.x * 32, r0 = blockIdx.y * 32;
#pragma unroll
  for (int i = 0; i < 4; ++i)
    tile[ty + i * 8][tx] = in[(size_t)(r0 + ty + i * 8) * C + c0 + tx];
  __syncthreads();
#pragma unroll
  for (int i = 0; i < 4; ++i)
    out[(size_t)(c0 + ty + i * 8) * R + r0 + tx] = __float2bfloat16(tile[tx][ty + i * 8]);
}

// ---------------- elementwise f32 -> bf16 (x4 vectorized) ----------------
__global__ __launch_bounds__(256) void k_f32_to_bf16(
    const float* __restrict__ in, bf16_t* __restrict__ out, int n4) {
  int i = blockIdx.x * 256 + threadIdx.x;
  if (i < n4) {
    float4 v = ((const float4*)in)[i];
    short4 o;
    o.x = (short)f2bf_u16(v.x);
    o.y = (short)f2bf_u16(v.y);
    o.z = (short)f2bf_u16(v.z);
    o.w = (short)f2bf_u16(v.w);
    ((short4*)out)[i] = o;
  }
}

// ---------------- pack qkv bias ----------------
__global__ __launch_bounds__(256) void k_pack_bias(
    const float* __restrict__ bq, const float* __restrict__ bk,
    const float* __restrict__ bv, float* __restrict__ out) {
  int i = blockIdx.x * 256 + threadIdx.x;  // 12 blocks * 256 = 3072
  float v = (i < 1024) ? bq[i] : (i < 2048) ? bk[i - 1024] : bv[i - 2048];
  out[i] = v;
}

// ---------------- GEMM: 128x128 tile, BK=64, XOR-swizzled LDS, optional split-K ----------
// epilogue modes:
//  0: out bf16 = acc + bias
//  1: out bf16 = relu(acc + bias)
//  3: out bf16 = (acc + bias) * (gcol < 1024 ? 0.125*log2e : 1)   [QKV]
//  4: f32 raw partial -> (kslice ? p1 : p0)                        [split-K]
#define GBK 64

__global__ __launch_bounds__(256, 2) void k_gemm(
    const bf16_t* __restrict__ A, const bf16_t* __restrict__ BT,
    const float* __restrict__ bias,
    float* __restrict__ p0, float* __restrict__ p1,
    void* __restrict__ Cout, int M, int N, int K,
    int lda, int ldb, int ldc, int mode, int nsplit) {
  __shared__ __align__(16) bf16_t Asm[128 * GBK];
  __shared__ __align__(16) bf16_t Bsm[128 * GBK];

  const int nbn = N / 128;
  const int nwg = gridDim.x;
  const int cpx = nwg >> 3;
  int wg = (blockIdx.x & 7) * cpx + (blockIdx.x >> 3);  // XCD swizzle (nwg % 8 == 0)
  int kslice = 0;
  if (nsplit == 2) { kslice = wg & 1; wg >>= 1; }
  const int mb = wg / nbn, nb = wg % nbn;
  const int row0 = mb * 128, col0 = nb * 128;
  A  += (size_t)kslice * K;   // column offset into full-K row
  BT += (size_t)kslice * K;

  const int tid = threadIdx.x;
  const int w = tid >> 6, lane = tid & 63;
  const int lr = lane & 15, lg = lane >> 4;
  const int wr = w >> 1, wc = w & 1;
  const int wbase = tid & 192;  // w*64

  f32x4 acc[4][4];
#pragma unroll
  for (int m = 0; m < 4; ++m)
#pragma unroll
    for (int n = 0; n < 4; ++n) acc[m][n] = (f32x4){0.f, 0.f, 0.f, 0.f};

  for (int k0 = 0; k0 < K; k0 += GBK) {
    __syncthreads();
    // stage A,B: 1024 chunks of 16B each; LDS linear [row][seg], source seg
    // pre-swizzled (sg = sl ^ (row&7)) so swizzled read recovers linear data.
#pragma unroll
    for (int i = 0; i < 4; ++i) {
      int c = i * 256 + tid;
      int row = c >> 3;
      int sg = (c & 7) ^ (row & 7);
      ASYNC_COPY16(Asm + (size_t)(i * 256 + wbase) * 8,
                   A + (size_t)(row0 + row) * lda + k0 + sg * 8);
    }
#pragma unroll
    for (int i = 0; i < 4; ++i) {
      int c = i * 256 + tid;
      int row = c >> 3;
      int sg = (c & 7) ^ (row & 7);
      ASYNC_COPY16(Bsm + (size_t)(i * 256 + wbase) * 8,
                   BT + (size_t)(col0 + row) * ldb + k0 + sg * 8);
    }
    __syncthreads();
#pragma unroll
    for (int kst = 0; kst < 2; ++kst) {
      const int sl = ((kst * 4 + lg) ^ (lr & 7)) * 8;  // swizzled seg offset (elements)
      s16x8 af[4], bfr[4];
#pragma unroll
      for (int m = 0; m < 4; ++m)
        af[m] = *(const s16x8*)(Asm + (size_t)(wr * 64 + m * 16 + lr) * GBK + sl);
#pragma unroll
      for (int n = 0; n < 4; ++n)
        bfr[n] = *(const s16x8*)(Bsm + (size_t)(wc * 64 + n * 16 + lr) * GBK + sl);
#pragma unroll
      for (int m = 0; m < 4; ++m)
#pragma unroll
        for (int n = 0; n < 4; ++n)
          acc[m][n] = __builtin_amdgcn_mfma_f32_16x16x32_bf16(af[m], bfr[n], acc[m][n], 0, 0, 0);
    }
  }

  float* outf = (kslice == 0) ? p0 : p1;
  bf16_t* outh = (bf16_t*)Cout;
#pragma unroll
  for (int m = 0; m < 4; ++m) {
    int grow = row0 + wr * 64 + m * 16 + lg * 4;
#pragma unroll
    for (int n = 0; n < 4; ++n) {
      int gcol = col0 + wc * 64 + n * 16 + lr;
      float bv = (mode == 4) ? 0.f : bias[gcol];
      float cs = (mode == 3 && gcol < 1024) ? 0.18033688f : 1.f;  // 0.125*log2(e)
#pragma unroll
      for (int r = 0; r < 4; ++r) {
        float v = (acc[m][n][r] + bv) * cs;
        size_t idx = (size_t)(grow + r) * ldc + gcol;
        if (mode == 4) {
          outf[idx] = v;
        } else {
          if (mode == 1) v = fmaxf(v, 0.f);
          outh[idx] = __float2bfloat16(v);
        }
      }
    }
  }
}

// ---------------- flash attention: 32x32 MFMA, lane-local softmax ----------------
__global__ __launch_bounds__(256, 2) void k_attn(
    const bf16_t* __restrict__ qkv, const int* __restrict__ mask,
    bf16_t* __restrict__ ctx) {
  const int bid = blockIdx.x;
  const int qt = bid & 15;          // 16 q-tiles of 128
  const int h  = (bid >> 4) & 15;
  const int b  = bid >> 8;
  const int tid = threadIdx.x;
  const int w = tid >> 6, lane = tid & 63;
  const int l31 = lane & 31, hi = lane >> 5;

  __shared__ __align__(16) bf16_t Kl[2][64][64];   // XOR-swizzled (seg ^= row&7)
  __shared__ __align__(16) bf16_t VT[2][64][72];   // V^T, stride 144B
  __shared__ __align__(16) float  mskf[2][64];

  const int tokb = b * SEQC;
  const int q0 = qt * 128 + w * 32;

  s16x8 qfrag[4];
  {
    const bf16_t* qp = qkv + (size_t)(tokb + q0 + l31) * 3072 + h * 64 + hi * 8;
#pragma unroll
    for (int s = 0; s < 4; ++s) qfrag[s] = *(const s16x8*)(qp + s * 16);
  }

  char* klc = (char*)&Kl[0][0][0];
  char* vtc = (char*)&VT[0][0][0];

  s16x8 vr[2];
  float mreg = 1.f;

#define STAGE_K(buf, kb)                                                              \
  {                                                                                   \
    _Pragma("unroll")                                                                 \
    for (int ii = 0; ii < 2; ++ii) {                                                  \
      int chunk = w * 2 + ii;                                                         \
      int row = chunk * 8 + (lane >> 3);                                              \
      int seg = (lane & 7) ^ (row & 7);                                               \
      const bf16_t* src = qkv + (size_t)(tokb + (kb) + row) * 3072 + 1024 + h * 64 + seg * 8; \
      ASYNC_COPY16(&Kl[buf][chunk * 8][0], src);                                      \
    }                                                                                 \
  }

#define LOAD_V(kb)                                                                    \
  {                                                                                   \
    _Pragma("unroll")                                                                 \
    for (int i = 0; i < 2; ++i) {                                                     \
      int c = tid + i * 256;                                                          \
      int key = c & 63, d0 = (c >> 6) * 8;                                            \
      vr[i] = *(const s16x8*)(qkv + (size_t)(tokb + (kb) + key) * 3072 + 2048 + h * 64 + d0); \
    }                                                                                 \
  }

#define WRITE_V(buf)                                                                  \
  {                                                                                   \
    _Pragma("unroll")                                                                 \
    for (int i = 0; i < 2; ++i) {                                                     \
      int c = tid + i * 256;                                                          \
      int key = c & 63, d0 = (c >> 6) * 8;                                            \
      const bf16_t* e = (const bf16_t*)&vr[i];                                        \
      _Pragma("unroll")                                                               \
      for (int j = 0; j < 8; ++j) {                                                   \
        int d = d0 + j;                                                               \
        *(bf16_t*)(vtc + (buf) * 9216 + d * 144 + (key >> 3) * 16 + (key & 7) * 2) = e[j]; \
      }                                                                               \
    }                                                                                 \
  }

  STAGE_K(0, 0)
  LOAD_V(0)
  if (tid < 64) mreg = mask[tokb + tid] ? 1.f : 0.f;
  WRITE_V(0)
  if (tid < 64) mskf[0][tid] = mreg;

  f32x16 o[2];
#pragma unroll
  for (int d = 0; d < 2; ++d)
#pragma unroll
    for (int i = 0; i < 16; ++i) o[d][i] = 0.f;
  float psum = 0.f;

  __syncthreads();

  for (int kt = 0; kt < SEQC / 64; ++kt) {
    const int kb = kt * 64;
    const int cur = kt & 1, nxt = cur ^ 1;
    const bool more = (kt < SEQC / 64 - 1);

    if (more) {
      STAGE_K(nxt, kb + 64)
      LOAD_V(kb + 64)
      if (tid < 64) mreg = mask[tokb + kb + 64 + tid] ? 1.f : 0.f;
    }

    f32x16 st[2];
#pragma unroll
    for (int kk = 0; kk < 2; ++kk)
#pragma unroll
      for (int i = 0; i < 16; ++i) st[kk][i] = 0.f;
#pragma unroll
    for (int step = 0; step < 4; ++step) {
#pragma unroll
      for (int kb2 = 0; kb2 < 2; ++kb2) {
        int key = kb2 * 32 + l31;
        int seg = (2 * step + hi) ^ (lane & 7);
        s16x8 kf = *(const s16x8*)(klc + cur * 8192 + key * 128 + seg * 16);
        st[kb2] = __builtin_amdgcn_mfma_f32_32x32x16_bf16(kf, qfrag[step], st[kb2], 0, 0, 0);
      }
    }

    s16x8 pf[4];
#pragma unroll
    for (int kb2 = 0; kb2 < 2; ++kb2) {
      float pa[16];
#pragma unroll
      for (int g = 0; g < 4; ++g) {
        f32x4 mm = *(const f32x4*)((char*)&mskf[cur][0] + (kb2 * 128 + g * 32 + hi * 16));
#pragma unroll
        for (int rr = 0; rr < 4; ++rr) {
          float e = __builtin_exp2f(st[kb2][g * 4 + rr]) * mm[rr];
          pa[g * 4 + rr] = e;
          psum += e;
        }
      }
      unsigned int wv[8];
#pragma unroll
      for (int u = 0; u < 8; ++u) wv[u] = cvt_pk_bf16(pa[2 * u], pa[2 * u + 1]);
      unsigned int x1 = hi ? wv[0] : wv[2]; x1 = (unsigned int)__shfl_xor((int)x1, 32);
      unsigned int x2 = hi ? wv[1] : wv[3]; x2 = (unsigned int)__shfl_xor((int)x2, 32);
      unsigned int x3 = hi ? wv[4] : wv[6]; x3 = (unsigned int)__shfl_xor((int)x3, 32);
      unsigned int x4 = hi ? wv[5] : wv[7]; x4 = (unsigned int)__shfl_xor((int)x4, 32);
      unsigned int f0[4], f1[4];
      f0[0] = hi ? x1 : wv[0];  f0[1] = hi ? x2 : wv[1];
      f0[2] = hi ? wv[2] : x1;  f0[3] = hi ? wv[3] : x2;
      f1[0] = hi ? x3 : wv[4];  f1[1] = hi ? x4 : wv[5];
      f1[2] = hi ? wv[6] : x3;  f1[3] = hi ? wv[7] : x4;
      pf[kb2 * 2 + 0] = __builtin_bit_cast(s16x8, *(ulong2*)f0);
      pf[kb2 * 2 + 1] = __builtin_bit_cast(s16x8, *(ulong2*)f1);
    }

#pragma unroll
    for (int ks = 0; ks < 4; ++ks) {
#pragma unroll
      for (int dblk = 0; dblk < 2; ++dblk) {
        int d = dblk * 32 + l31;
        s16x8 vf = *(const s16x8*)(vtc + cur * 9216 + d * 144 + (2 * ks + hi) * 16);
        o[dblk] = __builtin_amdgcn_mfma_f32_32x32x16_bf16(pf[ks], vf, o[dblk], 0, 0, 0);
      }
    }

    if (more) {
      WRITE_V(nxt)
      if (tid < 64) mskf[nxt][tid] = mreg;
    }

    __syncthreads();
  }

  psum += __shfl_xor(psum, 32);
  float rs[16];
#pragma unroll
  for (int r = 0; r < 16; ++r) {
    int qq = (r & 3) + 8 * (r >> 2) + 4 * hi;
    rs[r] = __shfl(psum, qq);
  }
#pragma unroll
  for (int dblk = 0; dblk < 2; ++dblk)
#pragma unroll
    for (int r = 0; r < 16; ++r) {
      int qq = (r & 3) + 8 * (r >> 2) + 4 * hi;
      int tok = tokb + q0 + qq;
      ctx[(size_t)tok * 1024 + h * 64 + dblk * 32 + l31] = __float2bfloat16(o[dblk][r] / rs[r]);
    }
#undef STAGE_K
#undef LOAD_V
#undef WRITE_V
}

// ---------------- fused split-K reduce + bias + residual + layernorm ----------------
// v = p0 + p1 + res + bias; out = LN(v)*g + be; optional bf16 copy.
__global__ __launch_bounds__(256) void k_ln_res2(
    const float* __restrict__ p0, const float* __restrict__ p1,
    const float* __restrict__ res, const float* __restrict__ bias,
    const float* __restrict__ g, const float* __restrict__ be,
    float* __restrict__ outf, bf16_t* __restrict__ outh) {
  const int row = blockIdx.x, tid = threadIdx.x;
  const size_t base = (size_t)row * D_MODELC;
  const float4 a  = ((const float4*)(p0 + base))[tid];
  const float4 bq = ((const float4*)(p1 + base))[tid];
  const float4 c  = ((const float4*)(res + base))[tid];
  const float4 bi = ((const float4*)bias)[tid];
  float4 v;
  v.x = a.x + bq.x + c.x + bi.x;
  v.y = a.y + bq.y + c.y + bi.y;
  v.z = a.z + bq.z + c.z + bi.z;
  v.w = a.w + bq.w + c.w + bi.w;
  float s1 = v.x + v.y + v.z + v.w;
  float s2 = v.x * v.x + v.y * v.y + v.z * v.z + v.w * v.w;
#pragma unroll
  for (int mm = 1; mm < 64; mm <<= 1) {
    s1 += __shfl_xor(s1, mm);
    s2 += __shfl_xor(s2, mm);
  }
  __shared__ float sa[4], sb[4];
  const int wv = tid >> 6;
  if ((tid & 63) == 0) { sa[wv] = s1; sb[wv] = s2; }
  __syncthreads();
  s1 = sa[0] + sa[1] + sa[2] + sa[3];
  s2 = sb[0] + sb[1] + sb[2] + sb[3];
  const float mu = s1 * (1.f / D_MODELC);
  const float var = s2 * (1.f / D_MODELC) - mu * mu;
  const float rsq = rsqrtf(var + 1e-5f);
  const float4 gg = ((const float4*)g)[tid];
  const float4 bb = ((const float4*)be)[tid];
  float4 oo;
  oo.x = (v.x - mu) * rsq * gg.x + bb.x;
  oo.y = (v.y - mu) * rsq * gg.y + bb.y;
  oo.z = (v.z - mu) * rsq * gg.z + bb.z;
  oo.w = (v.w - mu) * rsq * gg.w + bb.w;
  ((float4*)(outf + base))[tid] = oo;
  if (outh) {
    short4 ob;
    ob.x = (short)f2bf_u16(oo.x);
    ob.y = (short)f2bf_u16(oo.y);
    ob.z = (short)f2bf_u16(oo.z);
    ob.w = (short)f2bf_u16(oo.w);
    ((short4*)(outh + base))[tid] = ob;
  }
}

extern "C" void kernel_launch(void* const* d_in, const int* in_sizes, int n_in,
                              void* d_out, int out_size, void* d_ws, size_t ws_size,
                              hipStream_t stream) {
  (void)in_sizes; (void)n_in; (void)out_size; (void)ws_size;
  const float* x   = (const float*)d_in[0];
  const int* mask  = (const int*)d_in[1];
  const float* Wq  = (const float*)d_in[2];
  const float* bq  = (const float*)d_in[3];
  const float* Wk  = (const float*)d_in[4];
  const float* bk  = (const float*)d_in[5];
  const float* Wv  = (const float*)d_in[6];
  const float* bv  = (const float*)d_in[7];
  const float* Wo  = (const float*)d_in[8];
  const float* bo  = (const float*)d_in[9];
  const float* W1  = (const float*)d_in[10];
  const float* b1  = (const float*)d_in[11];
  const float* W2  = (const float*)d_in[12];
  const float* b2  = (const float*)d_in[13];
  const float* g1  = (const float*)d_in[14];
  const float* be1 = (const float*)d_in[15];
  const float* g2  = (const float*)d_in[16];
  const float* be2 = (const float*)d_in[17];

  char* ws = (char*)d_ws;
  const size_t D = D_MODELC, F = D_FFC, M = M_TOK;
  const size_t SZ_X16  = M * D * 2;        // 8.4 MB
  const size_t SZ_QKV  = M * 3 * D * 2;    // 25.2 MB
  bf16_t* x16   = (bf16_t*)ws;
  bf16_t* ff1   = (bf16_t*)ws;             // aliases x16+qkv (both dead by FF1)
  bf16_t* qkvb  = (bf16_t*)(ws + SZ_X16);
  size_t off = SZ_X16 + SZ_QKV;
  bf16_t* ctx   = (bf16_t*)(ws + off); off += M * D * 2;
  bf16_t* wqkvT = (bf16_t*)(ws + off); off += 3 * D * D * 2;
  bf16_t* woT   = (bf16_t*)(ws + off); off += D * D * 2;
  bf16_t* w1T   = (bf16_t*)(ws + off); off += D * F * 2;
  bf16_t* w2T   = (bf16_t*)(ws + off); off += D * F * 2;
  float*  partA = (float*)(ws + off);  off += M * D * 4;   // split-K partial 0
  float*  hbuf  = (float*)(ws + off);  off += M * D * 4;
  bf16_t* h16   = (bf16_t*)(ws + off); off += M * D * 2;
  float*  partB = (float*)(ws + off);  off += M * D * 4;   // split-K partial 1
  float*  bqkv  = (float*)(ws + off);  off += 3 * D * 4;

  // --- weight prep ---
  k_transpose_f32_bf16<<<dim3(32, 32), 256, 0, stream>>>(Wq, wqkvT, 1024, 1024);
  k_transpose_f32_bf16<<<dim3(32, 32), 256, 0, stream>>>(Wk, wqkvT + 1024 * 1024, 1024, 1024);
  k_transpose_f32_bf16<<<dim3(32, 32), 256, 0, stream>>>(Wv, wqkvT + 2 * 1024 * 1024, 1024, 1024);
  k_transpose_f32_bf16<<<dim3(32, 32), 256, 0, stream>>>(Wo, woT, 1024, 1024);
  k_transpose_f32_bf16<<<dim3(128, 32), 256, 0, stream>>>(W1, w1T, 1024, 4096);
  k_transpose_f32_bf16<<<dim3(32, 128), 256, 0, stream>>>(W2, w2T, 4096, 1024);
  k_f32_to_bf16<<<4096, 256, 0, stream>>>(x, x16, (int)(M * D / 4));
  k_pack_bias<<<12, 256, 0, stream>>>(bq, bk, bv, bqkv);

  // --- QKV projection: [4096][3072], Q pre-scaled by 0.125*log2e ---
  k_gemm<<<768, 256, 0, stream>>>(x16, wqkvT, bqkv, nullptr, nullptr, qkvb,
                                  4096, 3072, 1024, 1024, 1024, 3072, 3, 1);

  // --- attention: 512 blocks, 4 waves x 32 q-rows ---
  k_attn<<<BATCHC * N_HEADSC * (SEQC / 128), 256, 0, stream>>>(qkvb, mask, ctx);

  // --- output projection, split-K=2 (grid 512 = 2 blk/CU) -> partials ---
  k_gemm<<<512, 256, 0, stream>>>(ctx, woT, nullptr, partA, partB, nullptr,
                                  4096, 1024, 512, 1024, 1024, 1024, 4, 2);
  // LN1: p0+p1+x+bo -> hbuf (f32) + h16 (bf16)
  k_ln_res2<<<4096, 256, 0, stream>>>(partA, partB, x, bo, g1, be1, hbuf, h16);

  // --- FFN ---
  k_gemm<<<1024, 256, 0, stream>>>(h16, w1T, b1, nullptr, nullptr, ff1,
                                   4096, 4096, 1024, 1024, 1024, 4096, 1, 1);
  // FF2 split-K=2: each slice K=2048
  k_gemm<<<512, 256, 0, stream>>>(ff1, w2T, nullptr, partA, partB, nullptr,
                                  4096, 1024, 2048, 4096, 4096, 1024, 4, 2);
  // LN2: p0+p1+hbuf+b2 -> d_out (f32)
  k_ln_res2<<<4096, 256, 0, stream>>>(partA, partB, hbuf, b2, g2, be2, (float*)d_out, nullptr);
}

// Round 7
// 268.932 us; speedup vs baseline: 1.5643x; 1.0232x over previous
//
#include <hip/hip_runtime.h>
#include <hip/hip_bf16.h>

#define D_MODELC 1024
#define D_FFC    4096
#define N_HEADSC 16
#define BATCHC   2
#define SEQC     2048
#define M_TOK    (BATCHC*SEQC)   // 4096

typedef __attribute__((ext_vector_type(4)))  float f32x4;
typedef __attribute__((ext_vector_type(16))) float f32x16;
typedef __attribute__((ext_vector_type(8)))  short s16x8;
using bf16_t = __hip_bfloat16;

static __device__ __forceinline__ unsigned short f2bf_u16(float f) {
  bf16_t h = __float2bfloat16(f);
  return __builtin_bit_cast(unsigned short, h);
}

static __device__ __forceinline__ unsigned int cvt_pk_bf16(float lo, float hi2) {
  unsigned int r;
  asm("v_cvt_pk_bf16_f32 %0, %1, %2" : "=v"(r) : "v"(lo), "v"(hi2));
  return r;
}

#define PSWAP(a, b) asm volatile("v_permlane32_swap_b32 %0, %1" : "+v"(a), "+v"(b))

#define ASYNC_COPY16(dst_lds, src_g) \
  __builtin_amdgcn_global_load_lds((const __attribute__((address_space(1))) void*)(src_g), \
                                   (__attribute__((address_space(3))) void*)(dst_lds), 16, 0, 0)

// ---------------- transpose + convert: in f32 [R][C] -> out bf16 [C][R] ----------------
__global__ __launch_bounds__(256) void k_transpose_f32_bf16(
    const float* __restrict__ in, bf16_t* __restrict__ out, int R, int C) {
  __shared__ float tile[32][33];
  int tx = threadIdx.x & 31, ty = threadIdx.x >> 5;  // 32 x 8
  int c0 = blockIdx.x * 32, r0 = blockIdx.y * 32;
#pragma unroll
  for (int i = 0; i < 4; ++i)
    tile[ty + i * 8][tx] = in[(size_t)(r0 + ty + i * 8) * C + c0 + tx];
  __syncthreads();
#pragma unroll
  for (int i = 0; i < 4; ++i)
    out[(size_t)(c0 + ty + i * 8) * R + r0 + tx] = __float2bfloat16(tile[tx][ty + i * 8]);
}

// ---------------- elementwise f32 -> bf16 (x4 vectorized) ----------------
__global__ __launch_bounds__(256) void k_f32_to_bf16(
    const float* __restrict__ in, bf16_t* __restrict__ out, int n4) {
  int i = blockIdx.x * 256 + threadIdx.x;
  if (i < n4) {
    float4 v = ((const float4*)in)[i];
    short4 o;
    o.x = (short)f2bf_u16(v.x);
    o.y = (short)f2bf_u16(v.y);
    o.z = (short)f2bf_u16(v.z);
    o.w = (short)f2bf_u16(v.w);
    ((short4*)out)[i] = o;
  }
}

// ---------------- pack qkv bias ----------------
__global__ __launch_bounds__(256) void k_pack_bias(
    const float* __restrict__ bq, const float* __restrict__ bk,
    const float* __restrict__ bv, float* __restrict__ out) {
  int i = blockIdx.x * 256 + threadIdx.x;  // 12 blocks * 256 = 3072
  float v = (i < 1024) ? bq[i] : (i < 2048) ? bk[i - 1024] : bv[i - 2048];
  out[i] = v;
}

// ---------------- GEMM: 128x128 tile, BK=64, XOR-swizzled LDS, optional split-K ----------
#define GBK 64

__global__ __launch_bounds__(256, 2) void k_gemm(
    const bf16_t* __restrict__ A, const bf16_t* __restrict__ BT,
    const float* __restrict__ bias,
    float* __restrict__ p0, float* __restrict__ p1,
    void* __restrict__ Cout, int M, int N, int K,
    int lda, int ldb, int ldc, int mode, int nsplit) {
  __shared__ __align__(16) bf16_t Asm[128 * GBK];
  __shared__ __align__(16) bf16_t Bsm[128 * GBK];

  const int nbn = N / 128;
  const int nwg = gridDim.x;
  const int cpx = nwg >> 3;
  int wg = (blockIdx.x & 7) * cpx + (blockIdx.x >> 3);  // XCD swizzle (nwg % 8 == 0)
  int kslice = 0;
  if (nsplit == 2) { kslice = wg & 1; wg >>= 1; }
  const int mb = wg / nbn, nb = wg % nbn;
  const int row0 = mb * 128, col0 = nb * 128;
  A  += (size_t)kslice * K;
  BT += (size_t)kslice * K;

  const int tid = threadIdx.x;
  const int w = tid >> 6, lane = tid & 63;
  const int lr = lane & 15, lg = lane >> 4;
  const int wr = w >> 1, wc = w & 1;
  const int wbase = tid & 192;

  f32x4 acc[4][4];
#pragma unroll
  for (int m = 0; m < 4; ++m)
#pragma unroll
    for (int n = 0; n < 4; ++n) acc[m][n] = (f32x4){0.f, 0.f, 0.f, 0.f};

  for (int k0 = 0; k0 < K; k0 += GBK) {
    __syncthreads();
#pragma unroll
    for (int i = 0; i < 4; ++i) {
      int c = i * 256 + tid;
      int row = c >> 3;
      int sg = (c & 7) ^ (row & 7);
      ASYNC_COPY16(Asm + (size_t)(i * 256 + wbase) * 8,
                   A + (size_t)(row0 + row) * lda + k0 + sg * 8);
    }
#pragma unroll
    for (int i = 0; i < 4; ++i) {
      int c = i * 256 + tid;
      int row = c >> 3;
      int sg = (c & 7) ^ (row & 7);
      ASYNC_COPY16(Bsm + (size_t)(i * 256 + wbase) * 8,
                   BT + (size_t)(col0 + row) * ldb + k0 + sg * 8);
    }
    __syncthreads();
#pragma unroll
    for (int kst = 0; kst < 2; ++kst) {
      const int sl = ((kst * 4 + lg) ^ (lr & 7)) * 8;
      s16x8 af[4], bfr[4];
#pragma unroll
      for (int m = 0; m < 4; ++m)
        af[m] = *(const s16x8*)(Asm + (size_t)(wr * 64 + m * 16 + lr) * GBK + sl);
#pragma unroll
      for (int n = 0; n < 4; ++n)
        bfr[n] = *(const s16x8*)(Bsm + (size_t)(wc * 64 + n * 16 + lr) * GBK + sl);
#pragma unroll
      for (int m = 0; m < 4; ++m)
#pragma unroll
        for (int n = 0; n < 4; ++n)
          acc[m][n] = __builtin_amdgcn_mfma_f32_16x16x32_bf16(af[m], bfr[n], acc[m][n], 0, 0, 0);
    }
  }

  float* outf = (kslice == 0) ? p0 : p1;
  bf16_t* outh = (bf16_t*)Cout;
#pragma unroll
  for (int m = 0; m < 4; ++m) {
    int grow = row0 + wr * 64 + m * 16 + lg * 4;
#pragma unroll
    for (int n = 0; n < 4; ++n) {
      int gcol = col0 + wc * 64 + n * 16 + lr;
      float bv = (mode == 4) ? 0.f : bias[gcol];
      float cs = (mode == 3 && gcol < 1024) ? 0.18033688f : 1.f;  // 0.125*log2(e)
#pragma unroll
      for (int r = 0; r < 4; ++r) {
        float v = (acc[m][n][r] + bv) * cs;
        size_t idx = (size_t)(grow + r) * ldc + gcol;
        if (mode == 4) {
          outf[idx] = v;
        } else {
          if (mode == 1) v = fmaxf(v, 0.f);
          outh[idx] = __float2bfloat16(v);
        }
      }
    }
  }
}

// ---------------- flash attention: 32x32 MFMA, lane-local softmax, tr_b16 V ----------
// qkv: [4096][3072] bf16 (Q pre-scaled by 0.125*log2e, K at +1024, V at +2048)
// K: gload_lds + XOR-swizzled b128 reads. V: gload_lds into [key/4][d-subtile] tr-layout,
// PV B-frags via ds_read_b64_tr_b16 (ramp addr base+lane*8). P repack: cvt_pk + 4
// permlane32_swap per 32-key half (swap(w0,w2) -> pf word0/word2 for lo/hi lanes).
// Mask: per-tile all-valid flag -> skip mask path (any-mask still correct).
__global__ __launch_bounds__(256, 2) void k_attn(
    const bf16_t* __restrict__ qkv, const int* __restrict__ mask,
    bf16_t* __restrict__ ctx) {
  const int bid = blockIdx.x;
  const int qt = bid & 15;          // 16 q-tiles of 128
  const int h  = (bid >> 4) & 15;
  const int b  = bid >> 8;
  const int tid = threadIdx.x;
  const int w = tid >> 6, lane = tid & 63;
  const int l31 = lane & 31, hi = lane >> 5;
  const int wbase = tid & 192;

  __shared__ __align__(16) bf16_t Kl[2][64][64];   // XOR-swizzled (seg ^= row&7)
  __shared__ __align__(16) bf16_t Vl[2][4096];     // tr-subtiled V (see STAGE_V)
  __shared__ __align__(16) float  mskf[2][68];     // [64] = all-valid flag

  const int tokb = b * SEQC;
  const int q0 = qt * 128 + w * 32;

  s16x8 qfrag[4];
  {
    const bf16_t* qp = qkv + (size_t)(tokb + q0 + l31) * 3072 + h * 64 + hi * 8;
#pragma unroll
    for (int s = 0; s < 4; ++s) qfrag[s] = *(const s16x8*)(qp + s * 16);
  }

  char* klc = (char*)&Kl[0][0][0];
  bf16_t* Vl0 = &Vl[0][0];
  // LDS byte offset of Vl for tr_read addressing (AS3 pointer value = LDS offset)
  const unsigned vbase =
      (unsigned)(size_t)(__attribute__((address_space(3))) bf16_t*)Vl0 + lane * 8;

  float mreg = 1.f;

#define STAGE_K(buf, kb)                                                              \
  {                                                                                   \
    _Pragma("unroll")                                                                 \
    for (int ii = 0; ii < 2; ++ii) {                                                  \
      int chunk = w * 2 + ii;                                                         \
      int row = chunk * 8 + (lane >> 3);                                              \
      int seg = (lane & 7) ^ (row & 7);                                               \
      const bf16_t* src = qkv + (size_t)(tokb + (kb) + row) * 3072 + 1024 + h * 64 + seg * 8; \
      ASYNC_COPY16(&Kl[buf][chunk * 8][0], src);                                      \
    }                                                                                 \
  }

  // V tr-layout: elem(key,d) = L*64 + (key&3)*16 + (d&15),
  // L = f*16 + t*8 + dblk*4 + half*2 + (dc&1); f=key>>4, half=(key>>3)&1, t=(key>>2)&1,
  // dc=d>>4, dblk=dc>>1. Chunk c (16B) -> L=c>>3, key&3=(c&7)>>1, dlo=(c&1)*8.
#define STAGE_V(buf, kb)                                                              \
  {                                                                                   \
    _Pragma("unroll")                                                                 \
    for (int ii = 0; ii < 2; ++ii) {                                                  \
      const int c = tid + ii * 256;                                                   \
      const int L = c >> 3;                                                           \
      const int vf_ = L >> 4, vt_ = (L >> 3) & 1, vdb_ = (L >> 2) & 1;                \
      const int vh_ = (L >> 1) & 1, vdo_ = L & 1;                                     \
      const int vkey = 16 * vf_ + 8 * vh_ + 4 * vt_ + ((c & 7) >> 1);                 \
      const int vd = ((vdb_ * 2 + vdo_) << 4) + (c & 1) * 8;                          \
      const bf16_t* vsrc = qkv + (size_t)(tokb + (kb) + vkey) * 3072 + 2048 + h * 64 + vd; \
      ASYNC_COPY16(Vl0 + (size_t)(buf) * 4096 + (size_t)(ii * 256 + wbase) * 8, vsrc); \
    }                                                                                 \
  }

#define STAGE_M(buf, kb)                                                              \
  {                                                                                   \
    if (w == 0) {                                                                     \
      mreg = mask[tokb + (kb) + lane] ? 1.f : 0.f;                                    \
      mskf[buf][lane] = mreg;                                                         \
      unsigned long long z = __ballot(mreg == 0.f);                                   \
      if (lane == 0) mskf[buf][64] = (z == 0ull) ? 1.f : 0.f;                         \
    }                                                                                 \
  }

  // ---- prologue: stage tile 0 ----
  STAGE_K(0, 0)
  STAGE_V(0, 0)
  STAGE_M(0, 0)

  f32x16 o[2];
#pragma unroll
  for (int d = 0; d < 2; ++d)
#pragma unroll
    for (int i = 0; i < 16; ++i) o[d][i] = 0.f;
  float psum = 0.f;

  __syncthreads();

  for (int kt = 0; kt < SEQC / 64; ++kt) {
    const int kb = kt * 64;
    const int cur = kt & 1, nxt = cur ^ 1;
    const bool more = (kt < SEQC / 64 - 1);

    // 1. issue next-tile staging (all async into nxt)
    if (more) {
      STAGE_K(nxt, kb + 64)
      STAGE_V(nxt, kb + 64)
      STAGE_M(nxt, kb + 64)
    }

    // 2. swapped QK^T
    f32x16 st[2];
#pragma unroll
    for (int kk = 0; kk < 2; ++kk)
#pragma unroll
      for (int i = 0; i < 16; ++i) st[kk][i] = 0.f;
#pragma unroll
    for (int step = 0; step < 4; ++step) {
#pragma unroll
      for (int kb2 = 0; kb2 < 2; ++kb2) {
        int key = kb2 * 32 + l31;
        int seg = (2 * step + hi) ^ (lane & 7);
        s16x8 kf = *(const s16x8*)(klc + cur * 8192 + key * 128 + seg * 16);
        st[kb2] = __builtin_amdgcn_mfma_f32_32x32x16_bf16(kf, qfrag[step], st[kb2], 0, 0, 0);
      }
    }

    // 3. issue PV tr_reads now; latency hides under softmax
    const unsigned va = vbase + cur * 8192;
    ulong tr[4][2][2];
#pragma unroll
    for (int f = 0; f < 4; ++f)
#pragma unroll
      for (int db = 0; db < 2; ++db)
        asm volatile("ds_read_b64_tr_b16 %0, %2 offset:%c3\n\t"
                     "ds_read_b64_tr_b16 %1, %2 offset:%c4"
                     : "=v"(tr[f][db][0]), "=v"(tr[f][db][1])
                     : "v"(va), "i"((f * 16 + db * 4) * 128), "i"((f * 16 + 8 + db * 4) * 128));

    // 4. softmax (lane-local) + pack via cvt_pk + permlane32_swap
    const bool allv = (mskf[cur][64] != 0.f);
    s16x8 pf[4];
#pragma unroll
    for (int kb2 = 0; kb2 < 2; ++kb2) {
      float pa[16];
      if (allv) {
#pragma unroll
        for (int i = 0; i < 16; ++i) {
          float e = __builtin_exp2f(st[kb2][i]);
          pa[i] = e;
          psum += e;
        }
      } else {
#pragma unroll
        for (int g = 0; g < 4; ++g) {
          f32x4 mm = *(const f32x4*)((char*)&mskf[cur][0] + (kb2 * 128 + g * 32 + hi * 16));
#pragma unroll
          for (int rr = 0; rr < 4; ++rr) {
            float e = __builtin_exp2f(st[kb2][g * 4 + rr]) * mm[rr];
            pa[g * 4 + rr] = e;
            psum += e;
          }
        }
      }
      unsigned int wv[8];
#pragma unroll
      for (int u = 0; u < 8; ++u) wv[u] = cvt_pk_bf16(pa[2 * u], pa[2 * u + 1]);
      // swap(w0,w2): out0 = [lo|lo] = pf word0, out1 = [hi|hi] = pf word2
      unsigned int a0 = wv[0], b0 = wv[2]; PSWAP(a0, b0);
      unsigned int a1 = wv[1], b1 = wv[3]; PSWAP(a1, b1);
      unsigned int a2 = wv[4], b2 = wv[6]; PSWAP(a2, b2);
      unsigned int a3 = wv[5], b3 = wv[7]; PSWAP(a3, b3);
      uint4 u0 = {a0, a1, b0, b1};
      uint4 u1 = {a2, a3, b2, b3};
      pf[kb2 * 2 + 0] = __builtin_bit_cast(s16x8, u0);
      pf[kb2 * 2 + 1] = __builtin_bit_cast(s16x8, u1);
    }

    // 5. PV (wait for tr_reads; fence against MFMA hoist past the asm waitcnt)
    asm volatile("s_waitcnt lgkmcnt(0)" ::: "memory");
    __builtin_amdgcn_sched_barrier(0);
#pragma unroll
    for (int f = 0; f < 4; ++f)
#pragma unroll
      for (int db = 0; db < 2; ++db) {
        ulong2 uv = {tr[f][db][0], tr[f][db][1]};
        s16x8 vfr = __builtin_bit_cast(s16x8, uv);
        o[db] = __builtin_amdgcn_mfma_f32_32x32x16_bf16(pf[f], vfr, o[db], 0, 0, 0);
      }

    // 6. single barrier (buffer parity; also drains staging vmcnt)
    __syncthreads();
  }

  psum += __shfl_xor(psum, 32);
  float rs[16];
#pragma unroll
  for (int r = 0; r < 16; ++r) {
    int qq = (r & 3) + 8 * (r >> 2) + 4 * hi;
    rs[r] = __shfl(psum, qq);
  }
#pragma unroll
  for (int dblk = 0; dblk < 2; ++dblk)
#pragma unroll
    for (int r = 0; r < 16; ++r) {
      int qq = (r & 3) + 8 * (r >> 2) + 4 * hi;
      int tok = tokb + q0 + qq;
      ctx[(size_t)tok * 1024 + h * 64 + dblk * 32 + l31] = __float2bfloat16(o[dblk][r] / rs[r]);
    }
#undef STAGE_K
#undef STAGE_V
#undef STAGE_M
}

// ---------------- fused split-K reduce + bias + residual + layernorm ----------------
__global__ __launch_bounds__(256) void k_ln_res2(
    const float* __restrict__ p0, const float* __restrict__ p1,
    const float* __restrict__ res, const float* __restrict__ bias,
    const float* __restrict__ g, const float* __restrict__ be,
    float* __restrict__ outf, bf16_t* __restrict__ outh) {
  const int row = blockIdx.x, tid = threadIdx.x;
  const size_t base = (size_t)row * D_MODELC;
  const float4 a  = ((const float4*)(p0 + base))[tid];
  const float4 bq = ((const float4*)(p1 + base))[tid];
  const float4 c  = ((const float4*)(res + base))[tid];
  const float4 bi = ((const float4*)bias)[tid];
  float4 v;
  v.x = a.x + bq.x + c.x + bi.x;
  v.y = a.y + bq.y + c.y + bi.y;
  v.z = a.z + bq.z + c.z + bi.z;
  v.w = a.w + bq.w + c.w + bi.w;
  float s1 = v.x + v.y + v.z + v.w;
  float s2 = v.x * v.x + v.y * v.y + v.z * v.z + v.w * v.w;
#pragma unroll
  for (int mm = 1; mm < 64; mm <<= 1) {
    s1 += __shfl_xor(s1, mm);
    s2 += __shfl_xor(s2, mm);
  }
  __shared__ float sa[4], sb[4];
  const int wv = tid >> 6;
  if ((tid & 63) == 0) { sa[wv] = s1; sb[wv] = s2; }
  __syncthreads();
  s1 = sa[0] + sa[1] + sa[2] + sa[3];
  s2 = sb[0] + sb[1] + sb[2] + sb[3];
  const float mu = s1 * (1.f / D_MODELC);
  const float var = s2 * (1.f / D_MODELC) - mu * mu;
  const float rsq = rsqrtf(var + 1e-5f);
  const float4 gg = ((const float4*)g)[tid];
  const float4 bb = ((const float4*)be)[tid];
  float4 oo;
  oo.x = (v.x - mu) * rsq * gg.x + bb.x;
  oo.y = (v.y - mu) * rsq * gg.y + bb.y;
  oo.z = (v.z - mu) * rsq * gg.z + bb.z;
  oo.w = (v.w - mu) * rsq * gg.w + bb.w;
  ((float4*)(outf + base))[tid] = oo;
  if (outh) {
    short4 ob;
    ob.x = (short)f2bf_u16(oo.x);
    ob.y = (short)f2bf_u16(oo.y);
    ob.z = (short)f2bf_u16(oo.z);
    ob.w = (short)f2bf_u16(oo.w);
    ((short4*)(outh + base))[tid] = ob;
  }
}

extern "C" void kernel_launch(void* const* d_in, const int* in_sizes, int n_in,
                              void* d_out, int out_size, void* d_ws, size_t ws_size,
                              hipStream_t stream) {
  (void)in_sizes; (void)n_in; (void)out_size; (void)ws_size;
  const float* x   = (const float*)d_in[0];
  const int* mask  = (const int*)d_in[1];
  const float* Wq  = (const float*)d_in[2];
  const float* bq  = (const float*)d_in[3];
  const float* Wk  = (const float*)d_in[4];
  const float* bk  = (const float*)d_in[5];
  const float* Wv  = (const float*)d_in[6];
  const float* bv  = (const float*)d_in[7];
  const float* Wo  = (const float*)d_in[8];
  const float* bo  = (const float*)d_in[9];
  const float* W1  = (const float*)d_in[10];
  const float* b1  = (const float*)d_in[11];
  const float* W2  = (const float*)d_in[12];
  const float* b2  = (const float*)d_in[13];
  const float* g1  = (const float*)d_in[14];
  const float* be1 = (const float*)d_in[15];
  const float* g2  = (const float*)d_in[16];
  const float* be2 = (const float*)d_in[17];

  char* ws = (char*)d_ws;
  const size_t D = D_MODELC, F = D_FFC, M = M_TOK;
  const size_t SZ_X16  = M * D * 2;
  const size_t SZ_QKV  = M * 3 * D * 2;
  bf16_t* x16   = (bf16_t*)ws;
  bf16_t* ff1   = (bf16_t*)ws;             // aliases x16+qkv (both dead by FF1)
  bf16_t* qkvb  = (bf16_t*)(ws + SZ_X16);
  size_t off = SZ_X16 + SZ_QKV;
  bf16_t* ctx   = (bf16_t*)(ws + off); off += M * D * 2;
  bf16_t* wqkvT = (bf16_t*)(ws + off); off += 3 * D * D * 2;
  bf16_t* woT   = (bf16_t*)(ws + off); off += D * D * 2;
  bf16_t* w1T   = (bf16_t*)(ws + off); off += D * F * 2;
  bf16_t* w2T   = (bf16_t*)(ws + off); off += D * F * 2;
  float*  partA = (float*)(ws + off);  off += M * D * 4;
  float*  hbuf  = (float*)(ws + off);  off += M * D * 4;
  bf16_t* h16   = (bf16_t*)(ws + off); off += M * D * 2;
  float*  partB = (float*)(ws + off);  off += M * D * 4;
  float*  bqkv  = (float*)(ws + off);  off += 3 * D * 4;

  // --- weight prep ---
  k_transpose_f32_bf16<<<dim3(32, 32), 256, 0, stream>>>(Wq, wqkvT, 1024, 1024);
  k_transpose_f32_bf16<<<dim3(32, 32), 256, 0, stream>>>(Wk, wqkvT + 1024 * 1024, 1024, 1024);
  k_transpose_f32_bf16<<<dim3(32, 32), 256, 0, stream>>>(Wv, wqkvT + 2 * 1024 * 1024, 1024, 1024);
  k_transpose_f32_bf16<<<dim3(32, 32), 256, 0, stream>>>(Wo, woT, 1024, 1024);
  k_transpose_f32_bf16<<<dim3(128, 32), 256, 0, stream>>>(W1, w1T, 1024, 4096);
  k_transpose_f32_bf16<<<dim3(32, 128), 256, 0, stream>>>(W2, w2T, 4096, 1024);
  k_f32_to_bf16<<<4096, 256, 0, stream>>>(x, x16, (int)(M * D / 4));
  k_pack_bias<<<12, 256, 0, stream>>>(bq, bk, bv, bqkv);

  // --- QKV projection: [4096][3072], Q pre-scaled by 0.125*log2e ---
  k_gemm<<<768, 256, 0, stream>>>(x16, wqkvT, bqkv, nullptr, nullptr, qkvb,
                                  4096, 3072, 1024, 1024, 1024, 3072, 3, 1);

  // --- attention: 512 blocks, 4 waves x 32 q-rows ---
  k_attn<<<BATCHC * N_HEADSC * (SEQC / 128), 256, 0, stream>>>(qkvb, mask, ctx);

  // --- output projection, split-K=2 -> partials ---
  k_gemm<<<512, 256, 0, stream>>>(ctx, woT, nullptr, partA, partB, nullptr,
                                  4096, 1024, 512, 1024, 1024, 1024, 4, 2);
  k_ln_res2<<<4096, 256, 0, stream>>>(partA, partB, x, bo, g1, be1, hbuf, h16);

  // --- FFN ---
  k_gemm<<<1024, 256, 0, stream>>>(h16, w1T, b1, nullptr, nullptr, ff1,
                                   4096, 4096, 1024, 1024, 1024, 4096, 1, 1);
  k_gemm<<<512, 256, 0, stream>>>(ff1, w2T, nullptr, partA, partB, nullptr,
                                  4096, 1024, 2048, 4096, 4096, 1024, 4, 2);
  k_ln_res2<<<4096, 256, 0, stream>>>(partA, partB, hbuf, b2, g2, be2, (float*)d_out, nullptr);
}

// Round 8
// 259.979 us; speedup vs baseline: 1.6181x; 1.0344x over previous
//
#include <hip/hip_runtime.h>
#include <hip/hip_bf16.h>

#define D_MODELC 1024
#define D_FFC    4096
#define N_HEADSC 16
#define BATCHC   2
#define SEQC     2048
#define M_TOK    (BATCHC*SEQC)   // 4096

typedef __attribute__((ext_vector_type(4)))  float f32x4;
typedef __attribute__((ext_vector_type(16))) float f32x16;
typedef __attribute__((ext_vector_type(8)))  short s16x8;
using bf16_t = __hip_bfloat16;

static __device__ __forceinline__ unsigned short f2bf_u16(float f) {
  bf16_t h = __float2bfloat16(f);
  return __builtin_bit_cast(unsigned short, h);
}

static __device__ __forceinline__ unsigned int cvt_pk_bf16(float lo, float hi2) {
  unsigned int r;
  asm("v_cvt_pk_bf16_f32 %0, %1, %2" : "=v"(r) : "v"(lo), "v"(hi2));
  return r;
}

#define PSWAP(a, b) asm volatile("v_permlane32_swap_b32 %0, %1" : "+v"(a), "+v"(b))

#define ASYNC_COPY16(dst_lds, src_g) \
  __builtin_amdgcn_global_load_lds((const __attribute__((address_space(1))) void*)(src_g), \
                                   (__attribute__((address_space(3))) void*)(dst_lds), 16, 0, 0)

// ---------------- batched transpose 1024x1024 f32 -> bf16^T (4 matrices) ----------------
__global__ __launch_bounds__(256) void k_transpose4(
    const float* __restrict__ s0, const float* __restrict__ s1,
    const float* __restrict__ s2, const float* __restrict__ s3,
    bf16_t* __restrict__ d0, bf16_t* __restrict__ d1,
    bf16_t* __restrict__ d2, bf16_t* __restrict__ d3) {
  const int z = blockIdx.z;
  const float* in = (z == 0) ? s0 : (z == 1) ? s1 : (z == 2) ? s2 : s3;
  bf16_t* out = (z == 0) ? d0 : (z == 1) ? d1 : (z == 2) ? d2 : d3;
  __shared__ float tile[32][33];
  int tx = threadIdx.x & 31, ty = threadIdx.x >> 5;
  int c0 = blockIdx.x * 32, r0 = blockIdx.y * 32;
#pragma unroll
  for (int i = 0; i < 4; ++i)
    tile[ty + i * 8][tx] = in[(size_t)(r0 + ty + i * 8) * 1024 + c0 + tx];
  __syncthreads();
#pragma unroll
  for (int i = 0; i < 4; ++i)
    out[(size_t)(c0 + ty + i * 8) * 1024 + r0 + tx] = __float2bfloat16(tile[tx][ty + i * 8]);
}

// ---------------- transpose + convert: in f32 [R][C] -> out bf16 [C][R] ----------------
__global__ __launch_bounds__(256) void k_transpose_f32_bf16(
    const float* __restrict__ in, bf16_t* __restrict__ out, int R, int C) {
  __shared__ float tile[32][33];
  int tx = threadIdx.x & 31, ty = threadIdx.x >> 5;
  int c0 = blockIdx.x * 32, r0 = blockIdx.y * 32;
#pragma unroll
  for (int i = 0; i < 4; ++i)
    tile[ty + i * 8][tx] = in[(size_t)(r0 + ty + i * 8) * C + c0 + tx];
  __syncthreads();
#pragma unroll
  for (int i = 0; i < 4; ++i)
    out[(size_t)(c0 + ty + i * 8) * R + r0 + tx] = __float2bfloat16(tile[tx][ty + i * 8]);
}

// ---------------- elementwise f32 -> bf16 (x4 vectorized) ----------------
__global__ __launch_bounds__(256) void k_f32_to_bf16(
    const float* __restrict__ in, bf16_t* __restrict__ out, int n4) {
  int i = blockIdx.x * 256 + threadIdx.x;
  if (i < n4) {
    float4 v = ((const float4*)in)[i];
    short4 o;
    o.x = (short)f2bf_u16(v.x);
    o.y = (short)f2bf_u16(v.y);
    o.z = (short)f2bf_u16(v.z);
    o.w = (short)f2bf_u16(v.w);
    ((short4*)out)[i] = o;
  }
}

// ---------------- pack qkv bias ----------------
__global__ __launch_bounds__(256) void k_pack_bias(
    const float* __restrict__ bq, const float* __restrict__ bk,
    const float* __restrict__ bv, float* __restrict__ out) {
  int i = blockIdx.x * 256 + threadIdx.x;
  float v = (i < 1024) ? bq[i] : (i < 2048) ? bk[i - 1024] : bv[i - 2048];
  out[i] = v;
}

// ---------------- GEMM: 128x128 tile, BK=64, XOR-swizzled LDS, optional split-K ----------
#define GBK 64

__global__ __launch_bounds__(256, 2) void k_gemm(
    const bf16_t* __restrict__ A, const bf16_t* __restrict__ BT,
    const float* __restrict__ bias,
    float* __restrict__ p0, float* __restrict__ p1,
    void* __restrict__ Cout, int M, int N, int K,
    int lda, int ldb, int ldc, int mode, int nsplit) {
  __shared__ __align__(16) bf16_t Asm[128 * GBK];
  __shared__ __align__(16) bf16_t Bsm[128 * GBK];

  const int nbn = N / 128;
  const int nwg = gridDim.x;
  const int cpx = nwg >> 3;
  int wg = (blockIdx.x & 7) * cpx + (blockIdx.x >> 3);  // XCD swizzle (nwg % 8 == 0)
  int kslice = 0;
  if (nsplit == 2) { kslice = wg & 1; wg >>= 1; }
  const int mb = wg / nbn, nb = wg % nbn;
  const int row0 = mb * 128, col0 = nb * 128;
  A  += (size_t)kslice * K;
  BT += (size_t)kslice * K;

  const int tid = threadIdx.x;
  const int w = tid >> 6, lane = tid & 63;
  const int lr = lane & 15, lg = lane >> 4;
  const int wr = w >> 1, wc = w & 1;
  const int wbase = tid & 192;

  f32x4 acc[4][4];
#pragma unroll
  for (int m = 0; m < 4; ++m)
#pragma unroll
    for (int n = 0; n < 4; ++n) acc[m][n] = (f32x4){0.f, 0.f, 0.f, 0.f};

  for (int k0 = 0; k0 < K; k0 += GBK) {
    __syncthreads();
#pragma unroll
    for (int i = 0; i < 4; ++i) {
      int c = i * 256 + tid;
      int row = c >> 3;
      int sg = (c & 7) ^ (row & 7);
      ASYNC_COPY16(Asm + (size_t)(i * 256 + wbase) * 8,
                   A + (size_t)(row0 + row) * lda + k0 + sg * 8);
    }
#pragma unroll
    for (int i = 0; i < 4; ++i) {
      int c = i * 256 + tid;
      int row = c >> 3;
      int sg = (c & 7) ^ (row & 7);
      ASYNC_COPY16(Bsm + (size_t)(i * 256 + wbase) * 8,
                   BT + (size_t)(col0 + row) * ldb + k0 + sg * 8);
    }
    __syncthreads();
#pragma unroll
    for (int kst = 0; kst < 2; ++kst) {
      const int sl = ((kst * 4 + lg) ^ (lr & 7)) * 8;
      s16x8 af[4], bfr[4];
#pragma unroll
      for (int m = 0; m < 4; ++m)
        af[m] = *(const s16x8*)(Asm + (size_t)(wr * 64 + m * 16 + lr) * GBK + sl);
#pragma unroll
      for (int n = 0; n < 4; ++n)
        bfr[n] = *(const s16x8*)(Bsm + (size_t)(wc * 64 + n * 16 + lr) * GBK + sl);
#pragma unroll
      for (int m = 0; m < 4; ++m)
#pragma unroll
        for (int n = 0; n < 4; ++n)
          acc[m][n] = __builtin_amdgcn_mfma_f32_16x16x32_bf16(af[m], bfr[n], acc[m][n], 0, 0, 0);
    }
  }

  float* outf = (kslice == 0) ? p0 : p1;
  bf16_t* outh = (bf16_t*)Cout;
#pragma unroll
  for (int m = 0; m < 4; ++m) {
    int grow = row0 + wr * 64 + m * 16 + lg * 4;
#pragma unroll
    for (int n = 0; n < 4; ++n) {
      int gcol = col0 + wc * 64 + n * 16 + lr;
      float bv = (mode == 4) ? 0.f : bias[gcol];
      float cs = (mode == 3 && gcol < 1024) ? 0.18033688f : 1.f;  // 0.125*log2(e)
#pragma unroll
      for (int r = 0; r < 4; ++r) {
        float v = (acc[m][n][r] + bv) * cs;
        size_t idx = (size_t)(grow + r) * ldc + gcol;
        if (mode == 4) {
          outf[idx] = v;
        } else {
          if (mode == 1) v = fmaxf(v, 0.f);
          outh[idx] = __float2bfloat16(v);
        }
      }
    }
  }
}

// ---------------- flash attention: 32x32 MFMA, K-split x2, deferred normalization -------
// Each block scans 1024 keys (half the sequence) for a 128-row q-tile; writes
// UNNORMALIZED f32 partial o (pA/pB, ctx layout) + per-(q,h) partial sums (psA/psB).
// No running max (p = 2^s exactly), so partials are additive; k_attn_merge normalizes.
// Grid 1024 = 4 blocks/CU -> 4 waves/SIMD.
__global__ __launch_bounds__(256, 4) void k_attn(
    const bf16_t* __restrict__ qkv, const int* __restrict__ mask,
    float* __restrict__ pA, float* __restrict__ pB,
    float* __restrict__ psA, float* __restrict__ psB) {
  const int bid = blockIdx.x;
  const int half = bid >> 9;
  const int inner = bid & 511;
  const int qt = inner & 15;
  const int h  = (inner >> 4) & 15;
  const int b  = inner >> 8;
  const int tid = threadIdx.x;
  const int w = tid >> 6, lane = tid & 63;
  const int l31 = lane & 31, hi = lane >> 5;
  const int wbase = tid & 192;

  __shared__ __align__(16) bf16_t Kl[2][64][64];   // XOR-swizzled (seg ^= row&7)
  __shared__ __align__(16) bf16_t Vl[2][4096];     // tr-subtiled V
  __shared__ __align__(16) float  mskf[2][68];     // [64] = all-valid flag

  const int tokb = b * SEQC;
  const int q0 = qt * 128 + w * 32;
  const int kb0 = half * (SEQC / 2);

  s16x8 qfrag[4];
  {
    const bf16_t* qp = qkv + (size_t)(tokb + q0 + l31) * 3072 + h * 64 + hi * 8;
#pragma unroll
    for (int s = 0; s < 4; ++s) qfrag[s] = *(const s16x8*)(qp + s * 16);
  }

  char* klc = (char*)&Kl[0][0][0];
  bf16_t* Vl0 = &Vl[0][0];
  const unsigned vbase =
      (unsigned)(size_t)(__attribute__((address_space(3))) bf16_t*)Vl0 + lane * 8;

  float mreg = 1.f;

#define STAGE_K(buf, kb)                                                              \
  {                                                                                   \
    _Pragma("unroll")                                                                 \
    for (int ii = 0; ii < 2; ++ii) {                                                  \
      int chunk = w * 2 + ii;                                                         \
      int row = chunk * 8 + (lane >> 3);                                              \
      int seg = (lane & 7) ^ (row & 7);                                               \
      const bf16_t* src = qkv + (size_t)(tokb + (kb) + row) * 3072 + 1024 + h * 64 + seg * 8; \
      ASYNC_COPY16(&Kl[buf][chunk * 8][0], src);                                      \
    }                                                                                 \
  }

#define STAGE_V(buf, kb)                                                              \
  {                                                                                   \
    _Pragma("unroll")                                                                 \
    for (int ii = 0; ii < 2; ++ii) {                                                  \
      const int c = tid + ii * 256;                                                   \
      const int L = c >> 3;                                                           \
      const int vf_ = L >> 4, vt_ = (L >> 3) & 1, vdb_ = (L >> 2) & 1;                \
      const int vh_ = (L >> 1) & 1, vdo_ = L & 1;                                     \
      const int vkey = 16 * vf_ + 8 * vh_ + 4 * vt_ + ((c & 7) >> 1);                 \
      const int vd = ((vdb_ * 2 + vdo_) << 4) + (c & 1) * 8;                          \
      const bf16_t* vsrc = qkv + (size_t)(tokb + (kb) + vkey) * 3072 + 2048 + h * 64 + vd; \
      ASYNC_COPY16(Vl0 + (size_t)(buf) * 4096 + (size_t)(ii * 256 + wbase) * 8, vsrc); \
    }                                                                                 \
  }

#define STAGE_M(buf, kb)                                                              \
  {                                                                                   \
    if (w == 0) {                                                                     \
      mreg = mask[tokb + (kb) + lane] ? 1.f : 0.f;                                    \
      mskf[buf][lane] = mreg;                                                         \
      unsigned long long z = __ballot(mreg == 0.f);                                   \
      if (lane == 0) mskf[buf][64] = (z == 0ull) ? 1.f : 0.f;                         \
    }                                                                                 \
  }

  // ---- prologue: stage first tile of this half ----
  STAGE_K(0, kb0)
  STAGE_V(0, kb0)
  STAGE_M(0, kb0)

  f32x16 o[2];
#pragma unroll
  for (int d = 0; d < 2; ++d)
#pragma unroll
    for (int i = 0; i < 16; ++i) o[d][i] = 0.f;
  float psum = 0.f;

  __syncthreads();

  for (int kt = 0; kt < SEQC / 128; ++kt) {   // 16 tiles of 64 keys
    const int kb = kb0 + kt * 64;
    const int cur = kt & 1, nxt = cur ^ 1;
    const bool more = (kt < SEQC / 128 - 1);

    // 1. issue next-tile staging (all async into nxt)
    if (more) {
      STAGE_K(nxt, kb + 64)
      STAGE_V(nxt, kb + 64)
      STAGE_M(nxt, kb + 64)
    }

    // 2. swapped QK^T
    f32x16 st[2];
#pragma unroll
    for (int kk = 0; kk < 2; ++kk)
#pragma unroll
      for (int i = 0; i < 16; ++i) st[kk][i] = 0.f;
#pragma unroll
    for (int step = 0; step < 4; ++step) {
#pragma unroll
      for (int kb2 = 0; kb2 < 2; ++kb2) {
        int key = kb2 * 32 + l31;
        int seg = (2 * step + hi) ^ (lane & 7);
        s16x8 kf = *(const s16x8*)(klc + cur * 8192 + key * 128 + seg * 16);
        st[kb2] = __builtin_amdgcn_mfma_f32_32x32x16_bf16(kf, qfrag[step], st[kb2], 0, 0, 0);
      }
    }

    // 3. softmax (lane-local) + pack via cvt_pk + permlane32_swap
    const bool allv = (mskf[cur][64] != 0.f);
    s16x8 pf[4];
#pragma unroll
    for (int kb2 = 0; kb2 < 2; ++kb2) {
      float pa[16];
      if (allv) {
#pragma unroll
        for (int i = 0; i < 16; ++i) {
          float e = __builtin_exp2f(st[kb2][i]);
          pa[i] = e;
          psum += e;
        }
      } else {
#pragma unroll
        for (int g = 0; g < 4; ++g) {
          f32x4 mm = *(const f32x4*)((char*)&mskf[cur][0] + (kb2 * 128 + g * 32 + hi * 16));
#pragma unroll
          for (int rr = 0; rr < 4; ++rr) {
            float e = __builtin_exp2f(st[kb2][g * 4 + rr]) * mm[rr];
            pa[g * 4 + rr] = e;
            psum += e;
          }
        }
      }
      unsigned int wv[8];
#pragma unroll
      for (int u = 0; u < 8; ++u) wv[u] = cvt_pk_bf16(pa[2 * u], pa[2 * u + 1]);
      unsigned int a0 = wv[0], b0 = wv[2]; PSWAP(a0, b0);
      unsigned int a1 = wv[1], b1 = wv[3]; PSWAP(a1, b1);
      unsigned int a2 = wv[4], b2 = wv[6]; PSWAP(a2, b2);
      unsigned int a3 = wv[5], b3 = wv[7]; PSWAP(a3, b3);
      uint4 u0 = {a0, a1, b0, b1};
      uint4 u1 = {a2, a3, b2, b3};
      pf[kb2 * 2 + 0] = __builtin_bit_cast(s16x8, u0);
      pf[kb2 * 2 + 1] = __builtin_bit_cast(s16x8, u1);
    }

    // 4. PV per d-block: batch 8 tr_reads, wait, 4 MFMA (halves tr liveness vs all-16)
    const unsigned va = vbase + cur * 8192;
#pragma unroll
    for (int db = 0; db < 2; ++db) {
      ulong tr[4][2];
#pragma unroll
      for (int f = 0; f < 4; ++f)
        asm volatile("ds_read_b64_tr_b16 %0, %2 offset:%c3\n\t"
                     "ds_read_b64_tr_b16 %1, %2 offset:%c4"
                     : "=v"(tr[f][0]), "=v"(tr[f][1])
                     : "v"(va), "i"((f * 16 + db * 4) * 128), "i"((f * 16 + 8 + db * 4) * 128));
      asm volatile("s_waitcnt lgkmcnt(0)" ::: "memory");
      __builtin_amdgcn_sched_barrier(0);
#pragma unroll
      for (int f = 0; f < 4; ++f) {
        ulong2 uv = {tr[f][0], tr[f][1]};
        s16x8 vfr = __builtin_bit_cast(s16x8, uv);
        o[db] = __builtin_amdgcn_mfma_f32_32x32x16_bf16(pf[f], vfr, o[db], 0, 0, 0);
      }
    }

    // 5. single barrier (buffer parity; also drains staging)
    __syncthreads();
  }

  // ---- write unnormalized partials ----
  psum += __shfl_xor(psum, 32);   // full 64-key-tile sums for q = l31 (this half)
  float* po = half ? pB : pA;
  float* ps = half ? psB : psA;
#pragma unroll
  for (int dblk = 0; dblk < 2; ++dblk)
#pragma unroll
    for (int r = 0; r < 16; ++r) {
      int qq = (r & 3) + 8 * (r >> 2) + 4 * hi;
      int tok = tokb + q0 + qq;
      po[(size_t)tok * 1024 + h * 64 + dblk * 32 + l31] = o[dblk][r];
    }
  if (hi == 0)
    ps[(size_t)(tokb + q0 + l31) * 16 + h] = psum;
#undef STAGE_K
#undef STAGE_V
#undef STAGE_M
}

// ---------------- attention merge: ctx = (pA+pB) / (psA+psB) -> bf16 ----------------
__global__ __launch_bounds__(256) void k_attn_merge(
    const float* __restrict__ pA, const float* __restrict__ pB,
    const float* __restrict__ psA, const float* __restrict__ psB,
    bf16_t* __restrict__ ctx) {
  const int row = blockIdx.x, tid = threadIdx.x;
  const size_t base = (size_t)row * 1024;
  const float4 a = ((const float4*)(pA + base))[tid];
  const float4 b = ((const float4*)(pB + base))[tid];
  const int hh = tid >> 4;
  const float rs = psA[row * 16 + hh] + psB[row * 16 + hh];
  const float inv = 1.f / rs;
  short4 ob;
  ob.x = (short)f2bf_u16((a.x + b.x) * inv);
  ob.y = (short)f2bf_u16((a.y + b.y) * inv);
  ob.z = (short)f2bf_u16((a.z + b.z) * inv);
  ob.w = (short)f2bf_u16((a.w + b.w) * inv);
  ((short4*)(ctx + base))[tid] = ob;
}

// ---------------- fused split-K reduce + bias + residual + layernorm ----------------
__global__ __launch_bounds__(256) void k_ln_res2(
    const float* __restrict__ p0, const float* __restrict__ p1,
    const float* __restrict__ res, const float* __restrict__ bias,
    const float* __restrict__ g, const float* __restrict__ be,
    float* __restrict__ outf, bf16_t* __restrict__ outh) {
  const int row = blockIdx.x, tid = threadIdx.x;
  const size_t base = (size_t)row * D_MODELC;
  const float4 a  = ((const float4*)(p0 + base))[tid];
  const float4 bq = ((const float4*)(p1 + base))[tid];
  const float4 c  = ((const float4*)(res + base))[tid];
  const float4 bi = ((const float4*)bias)[tid];
  float4 v;
  v.x = a.x + bq.x + c.x + bi.x;
  v.y = a.y + bq.y + c.y + bi.y;
  v.z = a.z + bq.z + c.z + bi.z;
  v.w = a.w + bq.w + c.w + bi.w;
  float s1 = v.x + v.y + v.z + v.w;
  float s2 = v.x * v.x + v.y * v.y + v.z * v.z + v.w * v.w;
#pragma unroll
  for (int mm = 1; mm < 64; mm <<= 1) {
    s1 += __shfl_xor(s1, mm);
    s2 += __shfl_xor(s2, mm);
  }
  __shared__ float sa[4], sb[4];
  const int wv = tid >> 6;
  if ((tid & 63) == 0) { sa[wv] = s1; sb[wv] = s2; }
  __syncthreads();
  s1 = sa[0] + sa[1] + sa[2] + sa[3];
  s2 = sb[0] + sb[1] + sb[2] + sb[3];
  const float mu = s1 * (1.f / D_MODELC);
  const float var = s2 * (1.f / D_MODELC) - mu * mu;
  const float rsq = rsqrtf(var + 1e-5f);
  const float4 gg = ((const float4*)g)[tid];
  const float4 bb = ((const float4*)be)[tid];
  float4 oo;
  oo.x = (v.x - mu) * rsq * gg.x + bb.x;
  oo.y = (v.y - mu) * rsq * gg.y + bb.y;
  oo.z = (v.z - mu) * rsq * gg.z + bb.z;
  oo.w = (v.w - mu) * rsq * gg.w + bb.w;
  ((float4*)(outf + base))[tid] = oo;
  if (outh) {
    short4 ob;
    ob.x = (short)f2bf_u16(oo.x);
    ob.y = (short)f2bf_u16(oo.y);
    ob.z = (short)f2bf_u16(oo.z);
    ob.w = (short)f2bf_u16(oo.w);
    ((short4*)(outh + base))[tid] = ob;
  }
}

extern "C" void kernel_launch(void* const* d_in, const int* in_sizes, int n_in,
                              void* d_out, int out_size, void* d_ws, size_t ws_size,
                              hipStream_t stream) {
  (void)in_sizes; (void)n_in; (void)out_size; (void)ws_size;
  const float* x   = (const float*)d_in[0];
  const int* mask  = (const int*)d_in[1];
  const float* Wq  = (const float*)d_in[2];
  const float* bq  = (const float*)d_in[3];
  const float* Wk  = (const float*)d_in[4];
  const float* bk  = (const float*)d_in[5];
  const float* Wv  = (const float*)d_in[6];
  const float* bv  = (const float*)d_in[7];
  const float* Wo  = (const float*)d_in[8];
  const float* bo  = (const float*)d_in[9];
  const float* W1  = (const float*)d_in[10];
  const float* b1  = (const float*)d_in[11];
  const float* W2  = (const float*)d_in[12];
  const float* b2  = (const float*)d_in[13];
  const float* g1  = (const float*)d_in[14];
  const float* be1 = (const float*)d_in[15];
  const float* g2  = (const float*)d_in[16];
  const float* be2 = (const float*)d_in[17];

  char* ws = (char*)d_ws;
  const size_t D = D_MODELC, F = D_FFC, M = M_TOK;
  const size_t SZ_X16  = M * D * 2;
  const size_t SZ_QKV  = M * 3 * D * 2;
  bf16_t* x16   = (bf16_t*)ws;
  bf16_t* ff1   = (bf16_t*)ws;             // aliases x16+qkv (both dead by FF1)
  bf16_t* qkvb  = (bf16_t*)(ws + SZ_X16);
  size_t off = SZ_X16 + SZ_QKV;
  bf16_t* ctx   = (bf16_t*)(ws + off); off += M * D * 2;
  bf16_t* wqkvT = (bf16_t*)(ws + off); off += 3 * D * D * 2;
  bf16_t* woT   = (bf16_t*)(ws + off); off += D * D * 2;
  bf16_t* w1T   = (bf16_t*)(ws + off); off += D * F * 2;
  bf16_t* w2T   = (bf16_t*)(ws + off); off += D * F * 2;
  float*  partA = (float*)(ws + off);  off += M * D * 4;   // attn partial 0 / Wo-FF2 split-K p0
  float*  hbuf  = (float*)(ws + off);  off += M * D * 4;
  bf16_t* h16   = (bf16_t*)(ws + off); off += M * D * 2;
  float*  partB = (float*)(ws + off);  off += M * D * 4;   // attn partial 1 / split-K p1
  float*  bqkv  = (float*)(ws + off);  off += 3 * D * 4;
  float*  psA   = (float*)(ws + off);  off += M * 16 * 4;  // attn partial row-sums
  float*  psB   = (float*)(ws + off);  off += M * 16 * 4;

  // --- weight prep ---
  k_transpose4<<<dim3(32, 32, 4), 256, 0, stream>>>(
      Wq, Wk, Wv, Wo, wqkvT, wqkvT + 1024 * 1024, wqkvT + 2 * 1024 * 1024, woT);
  k_transpose_f32_bf16<<<dim3(128, 32), 256, 0, stream>>>(W1, w1T, 1024, 4096);
  k_transpose_f32_bf16<<<dim3(32, 128), 256, 0, stream>>>(W2, w2T, 4096, 1024);
  k_f32_to_bf16<<<4096, 256, 0, stream>>>(x, x16, (int)(M * D / 4));
  k_pack_bias<<<12, 256, 0, stream>>>(bq, bk, bv, bqkv);

  // --- QKV projection: [4096][3072], Q pre-scaled by 0.125*log2e ---
  k_gemm<<<768, 256, 0, stream>>>(x16, wqkvT, bqkv, nullptr, nullptr, qkvb,
                                  4096, 3072, 1024, 1024, 1024, 3072, 3, 1);

  // --- attention: K-split x2, 1024 blocks (4/CU), then merge ---
  k_attn<<<1024, 256, 0, stream>>>(qkvb, mask, partA, partB, psA, psB);
  k_attn_merge<<<4096, 256, 0, stream>>>(partA, partB, psA, psB, ctx);

  // --- output projection, split-K=2 -> partials (reuses partA/partB) ---
  k_gemm<<<512, 256, 0, stream>>>(ctx, woT, nullptr, partA, partB, nullptr,
                                  4096, 1024, 512, 1024, 1024, 1024, 4, 2);
  k_ln_res2<<<4096, 256, 0, stream>>>(partA, partB, x, bo, g1, be1, hbuf, h16);

  // --- FFN ---
  k_gemm<<<1024, 256, 0, stream>>>(h16, w1T, b1, nullptr, nullptr, ff1,
                                   4096, 4096, 1024, 1024, 1024, 4096, 1, 1);
  k_gemm<<<512, 256, 0, stream>>>(ff1, w2T, nullptr, partA, partB, nullptr,
                                  4096, 1024, 2048, 4096, 4096, 1024, 4, 2);
  k_ln_res2<<<4096, 256, 0, stream>>>(partA, partB, hbuf, b2, g2, be2, (float*)d_out, nullptr);
}